// Round 10
// baseline (728.129 us; speedup 1.0000x reference)
//
#include <hip/hip_runtime.h>
#include <hip/hip_bf16.h>
#include <stdint.h>

#define DEVI __device__ __forceinline__

typedef __bf16 bf16x8 __attribute__((ext_vector_type(8)));
typedef float f32x4 __attribute__((ext_vector_type(4)));
typedef unsigned short us;
typedef unsigned long long ull;

DEVI float b2f(us u) { union { unsigned int i; float f; } v; v.i = ((unsigned int)u) << 16; return v.f; }
DEVI us f2b(float f) {
  union { unsigned int i; float f; } v; v.f = f;
  unsigned int r = (v.i + 0x7fffu + ((v.i >> 16) & 1u)) >> 16;
  return (us)r;
}

#define NEGINF (-__builtin_inff())

DEVI void gl2lds16(const us* g, us* l) {
  __builtin_amdgcn_global_load_lds(
      (const __attribute__((address_space(1))) unsigned int*)g,
      (__attribute__((address_space(3))) unsigned int*)l, 16, 0, 0);
}

// ---------------------------------------------------------------------------
// Runtime dtype detection. flags[0]: f32 inputs; flags[1]: byte-packed masks.
// ---------------------------------------------------------------------------
__global__ __launch_bounds__(256) void detect_flags(
    const unsigned int* __restrict__ xw, const unsigned int* __restrict__ mw,
    int* __restrict__ flags) {
  const int t = threadIdx.x;
  int cnt = 0, big = 0;
  for (int i = t; i < 4096; i += 256) {
    unsigned int w = xw[i];
    us lo = (us)(w & 0xffffu);
    float a = fabsf(b2f(lo));
    cnt += ((lo == 0) || (a >= 1e-8f && a <= 256.f)) ? 1 : 0;
    big |= (mw[i] > 1u) ? 1 : 0;
  }
  for (int o = 32; o; o >>= 1) { cnt += __shfl_down(cnt, o); big |= __shfl_down(big, o); }
  __shared__ int sc[4], sb[4];
  if ((t & 63) == 0) { sc[t >> 6] = cnt; sb[t >> 6] = big; }
  __syncthreads();
  if (t == 0) {
    flags[0] = (sc[0] + sc[1] + sc[2] + sc[3] < 2048) ? 1 : 0;
    flags[1] = (sb[0] | sb[1] | sb[2] | sb[3]);
  }
}

__global__ __launch_bounds__(256) void cvt_bf16(
    const void* __restrict__ src, us* __restrict__ dst, int n,
    const int* __restrict__ flags) {
  const int f32mode = flags[0];
  int idx = (blockIdx.x * 256 + threadIdx.x) * 4;
  if (idx >= n) return;
  if (f32mode) {
    const float* s = (const float*)src;
    float4 v = *(const float4*)(s + idx);
    dst[idx] = f2b(v.x); dst[idx + 1] = f2b(v.y);
    dst[idx + 2] = f2b(v.z); dst[idx + 3] = f2b(v.w);
  } else {
    *(uint2*)(dst + idx) = *(const uint2*)((const us*)src + idx);
  }
}

struct P10 { const void* p[10]; };
__global__ __launch_bounds__(256) void cvt_small(P10 ps, us* __restrict__ dst,
                                                 const int* __restrict__ flags) {
  const int offs[11] = {0, 1024, 2048, 3072, 5120, 6144, 12288, 15360, 16384, 20480, 21504};
  int idx = blockIdx.x * 256 + threadIdx.x;
  if (idx >= 21504) return;
  int seg = 0;
#pragma unroll
  for (int i = 1; i < 10; ++i) seg += (idx >= offs[i]) ? 1 : 0;
  int local = idx - offs[seg];
  float v = flags[0] ? ((const float*)ps.p[seg])[local]
                     : b2f(((const us*)ps.p[seg])[local]);
  dst[idx] = f2b(v);
}

// Vectorized 64x64 convert+transpose: W (K,N) f32/bf16 -> WT (N,K) bf16.
__global__ __launch_bounds__(256) void transpose_cvt64(
    const void* __restrict__ W, us* __restrict__ WT, int K, int N,
    const int* __restrict__ flags) {
  __shared__ __attribute__((aligned(16))) us tile[64 * 72];
  const int f32m = flags[0];
  const int k0 = blockIdx.x * 64, n0 = blockIdx.y * 64;
  const int t = threadIdx.x;
  const int row = t >> 2, colb = (t & 3) * 16;
  const int sw = ((row >> 4) & 3) << 4;
  us tmp[16];
  if (f32m) {
    const float* src = (const float*)W + (size_t)(k0 + row) * N + n0 + colb;
#pragma unroll
    for (int i = 0; i < 16; i += 4) {
      float4 v = *(const float4*)(src + i);
      tmp[i] = f2b(v.x); tmp[i + 1] = f2b(v.y); tmp[i + 2] = f2b(v.z); tmp[i + 3] = f2b(v.w);
    }
  } else {
    const us* src = (const us*)W + (size_t)(k0 + row) * N + n0 + colb;
    *(uint4*)tmp = *(const uint4*)src;
    *(uint4*)(tmp + 8) = *(const uint4*)(src + 8);
  }
  *(uint4*)&tile[row * 72 + (colb ^ sw)] = *(uint4*)tmp;
  *(uint4*)&tile[row * 72 + (colb ^ sw) + 8] = *(uint4*)(tmp + 8);
  __syncthreads();
  const int orow = t >> 2, ocolb = (t & 3) * 16;
  const int pc = (orow & 15) | ((orow & 48) ^ (ocolb & 48));
  us out[16];
#pragma unroll
  for (int i = 0; i < 16; ++i) out[i] = tile[(ocolb + i) * 72 + pc];
  us* dst = WT + (size_t)(n0 + orow) * K + k0 + ocolb;
  *(uint4*)dst = *(uint4*)out;
  *(uint4*)(dst + 8) = *(uint4*)(out + 8);
}

struct P3 { const void* p[3]; };
__global__ __launch_bounds__(256) void pack_mask3(P3 ms, ull* __restrict__ bits,
                                                  const int* __restrict__ flags) {
  const int bytemode = flags[1];
  const void* m = ms.p[blockIdx.y];
  ull* out = bits + (size_t)blockIdx.y * 32768;
  int wv = blockIdx.x * 4 + (threadIdx.x >> 6);
  int lane = threadIdx.x & 63;
  for (int w = 0; w < 16; ++w) {
    int v;
    if (bytemode) v = ((const unsigned char*)m)[(size_t)wv * 1024 + w * 64 + lane];
    else          v = ((const int*)m)[(size_t)wv * 1024 + w * 64 + lane];
    ull b = __ballot(v != 0);
    if (lane == 0) out[(size_t)wv * 16 + w] = b;
  }
}

__global__ __launch_bounds__(256) void hat_blockflags(
    const ull* __restrict__ starb, const ull* __restrict__ hatb, int* __restrict__ bf) {
  const int bt = blockIdx.x;
  const int b = bt >> 4, tt = bt & 15;
  const int t = threadIdx.x, wv = t >> 6, lane = t & 63;
  const int t0 = tt * 64;
  for (int k = 0; k < 4; ++k) {
    int ck = wv * 4 + k;
    ull sw = starb[(size_t)(b * 1024 + t0 + lane) * 16 + ck];
    ull hw = hatb[(size_t)(b * 1024 + t0 + lane) * 16 + ck];
    int f = (__ballot(sw != 0ull) ? 1 : 0) | (__ballot(hw != 0ull) ? 2 : 0);
    if (lane == 0) bf[bt * 16 + ck] = f;
  }
}

// V transpose to [bh][64(d)][T]
__global__ __launch_bounds__(256) void vtrans(
    const us* __restrict__ src, us* __restrict__ dst,
    int T, int stride, int colBase, int rowOff) {
  __shared__ __attribute__((aligned(16))) us tile[64][65];
  const int bh = blockIdx.y, b = bh >> 4, h = bh & 15;
  const int t0 = blockIdx.x * 64;
  const int t = threadIdx.x;
#pragma unroll
  for (int it = 0; it < 2; ++it) {
    int idx = it * 256 + t; int r = idx >> 3, c8 = (idx & 7) * 8;
    uint4 d4 = *(const uint4*)(src + (size_t)(rowOff + b * T + t0 + r) * stride + colBase + h * 64 + c8);
    const us* e = (const us*)&d4;
#pragma unroll
    for (int i = 0; i < 8; ++i) tile[r][c8 + i] = e[i];
  }
  __syncthreads();
#pragma unroll
  for (int it = 0; it < 2; ++it) {
    int idx = it * 256 + t; int d = idx >> 3, c8 = (idx & 7) * 8;
    us tmp[8];
#pragma unroll
    for (int i = 0; i < 8; ++i) tmp[i] = tile[c8 + i][d];
    *(uint4*)(dst + ((size_t)(bh * 64 + d)) * T + t0 + c8) = *(const uint4*)tmp;
  }
}

// Both self-attn V transposes (star z=0, hat z=1) in one launch.
__global__ __launch_bounds__(256) void vtrans_qkv(
    const us* __restrict__ src, us* __restrict__ dst0, us* __restrict__ dst1) {
  __shared__ __attribute__((aligned(16))) us tile[64][65];
  const int z = blockIdx.z;
  us* dst = z ? dst1 : dst0;
  const int rowOff = z ? 2048 : 0;
  const int bh = blockIdx.y, b = bh >> 4, h = bh & 15;
  const int t0 = blockIdx.x * 64;
  const int t = threadIdx.x;
#pragma unroll
  for (int it = 0; it < 2; ++it) {
    int idx = it * 256 + t; int r = idx >> 3, c8 = (idx & 7) * 8;
    uint4 d4 = *(const uint4*)(src + (size_t)(rowOff + b * 1024 + t0 + r) * 3072 + 2048 + h * 64 + c8);
    const us* e = (const us*)&d4;
#pragma unroll
    for (int i = 0; i < 8; ++i) tile[r][c8 + i] = e[i];
  }
  __syncthreads();
#pragma unroll
  for (int it = 0; it < 2; ++it) {
    int idx = it * 256 + t; int d = idx >> 3, c8 = (idx & 7) * 8;
    us tmp[8];
#pragma unroll
    for (int i = 0; i < 8; ++i) tmp[i] = tile[c8 + i][d];
    *(uint4*)(dst + ((size_t)(bh * 64 + d)) * 1024 + t0 + c8) = *(const uint4*)tmp;
  }
}

// ---------------------------------------------------------------------------
// LayerNorm + modulation
// ---------------------------------------------------------------------------
__global__ __launch_bounds__(256) void ln_affine(
    const void* __restrict__ xs, const void* __restrict__ xh,
    const us* __restrict__ gw, const us* __restrict__ bw,
    us* __restrict__ lnx, us* __restrict__ xn, const int* __restrict__ flags) {
  const int f32m = flags[0];
  const int row = blockIdx.x;
  const void* xp = (row < 2048) ? xs : xh;
  const size_t base = (size_t)(row & 2047) * 1024;
  const int t = threadIdx.x;
  float v[4]; float s = 0.f, ss = 0.f;
#pragma unroll
  for (int i = 0; i < 4; ++i) {
    size_t idx = base + i * 256 + t;
    float x = f32m ? ((const float*)xp)[idx] : b2f(((const us*)xp)[idx]);
    v[i] = x; s += x; ss += x * x;
  }
  for (int o = 32; o; o >>= 1) { s += __shfl_down(s, o); ss += __shfl_down(ss, o); }
  __shared__ float red[2][4];
  const int wv = t >> 6, lane = t & 63;
  if (lane == 0) { red[0][wv] = s; red[1][wv] = ss; }
  __syncthreads();
  s = red[0][0] + red[0][1] + red[0][2] + red[0][3];
  ss = red[1][0] + red[1][1] + red[1][2] + red[1][3];
  const float mean = s * (1.f / 1024.f);
  const float var = fmaxf(ss * (1.f / 1024.f) - mean * mean, 0.f);
  const float rstd = rsqrtf(var + 1e-6f);
  const size_t ro = (size_t)row * 1024;
#pragma unroll
  for (int i = 0; i < 4; ++i) {
    int c = i * 256 + t;
    float n = (v[i] - mean) * rstd;
    lnx[ro + c] = f2b(n);
    xn[ro + c] = f2b(n * b2f(gw[c]) + b2f(bw[c]));
  }
}

__global__ __launch_bounds__(256) void mod_ms(
    const us* __restrict__ lnx, const us* __restrict__ gada, us* __restrict__ ms) {
  const size_t idx = ((size_t)blockIdx.x * 256 + threadIdx.x) * 4;
  const int row = (int)(idx >> 10), c = (int)(idx & 1023);
  const size_t gb = (size_t)row * 6144;
#pragma unroll
  for (int i = 0; i < 4; ++i) {
    float sh = b2f(gada[gb + c + i]);
    float sc = b2f(gada[gb + 1024 + c + i]);
    ms[idx + i] = f2b(b2f(lnx[idx + i]) * (1.f + sc) + sh);
  }
}

__global__ __launch_bounds__(256) void ln_mod(
    const float* __restrict__ x1, const us* __restrict__ gada, us* __restrict__ m2) {
  const int row = blockIdx.x;
  const float* xp = x1 + (size_t)row * 1024;
  const int t = threadIdx.x;
  float v[4]; float s = 0.f, ss = 0.f;
#pragma unroll
  for (int i = 0; i < 4; ++i) { float x = xp[i * 256 + t]; v[i] = x; s += x; ss += x * x; }
  for (int o = 32; o; o >>= 1) { s += __shfl_down(s, o); ss += __shfl_down(ss, o); }
  __shared__ float red[2][4];
  const int wv = t >> 6, lane = t & 63;
  if (lane == 0) { red[0][wv] = s; red[1][wv] = ss; }
  __syncthreads();
  s = red[0][0] + red[0][1] + red[0][2] + red[0][3];
  ss = red[1][0] + red[1][1] + red[1][2] + red[1][3];
  const float mean = s * (1.f / 1024.f);
  const float var = fmaxf(ss * (1.f / 1024.f) - mean * mean, 0.f);
  const float rstd = rsqrtf(var + 1e-6f);
  const size_t gb = (size_t)row * 6144;
#pragma unroll
  for (int i = 0; i < 4; ++i) {
    int c = i * 256 + t;
    float n = (v[i] - mean) * rstd;
    float sh = b2f(gada[gb + 3072 + c]);
    float sc = b2f(gada[gb + 4096 + c]);
    m2[(size_t)row * 1024 + c] = f2b(n * (1.f + sc) + sh);
  }
}

// ---------------------------------------------------------------------------
// MFMA GEMM with counted-vmcnt double-buffer pipeline (r6-proven structure).
// ---------------------------------------------------------------------------
enum { EPI_BF16 = 0, EPI_SILU, EPI_GELU, EPI_GATE_XRES, EPI_GATE_OUT };

template <int EPI>
DEVI void gemm_epi(float v, int gmr, int gn, int N, void* out,
                   const us* gate, const void* res0, const void* res1,
                   const int* oflags) {
  const size_t oi = (size_t)gmr * N + gn;
  if constexpr (EPI == EPI_BF16) {
    ((us*)out)[oi] = f2b(v);
  } else if constexpr (EPI == EPI_SILU) {
    ((us*)out)[oi] = f2b(v / (1.f + __expf(-v)));
  } else if constexpr (EPI == EPI_GELU) {
    float u = 0.7978845608028654f * (v + 0.044715f * v * v * v);
    float th = 1.f - 2.f / (__expf(2.f * u) + 1.f);
    ((us*)out)[oi] = f2b(0.5f * v * (1.f + th));
  } else if constexpr (EPI == EPI_GATE_XRES) {
    float g = b2f(gate[(size_t)gmr * 6144 + gn]);
    const void* xr = (gmr < 2048) ? res0 : res1;
    size_t xi = (size_t)(gmr & 2047) * 1024 + gn;
    float x = oflags[0] ? ((const float*)xr)[xi] : b2f(((const us*)xr)[xi]);
    ((float*)out)[oi] = x + g * v;
  } else {
    float g = b2f(gate[(size_t)gmr * 6144 + gn]);
    float x = ((const float*)res0)[oi];
    float r2 = x + g * v;
    if (oflags[0]) ((float*)out)[oi] = r2;
    else ((us*)out)[oi] = f2b(r2);
  }
}

template <int EPI>
__global__ __launch_bounds__(256) void gemm_bt(
    const us* __restrict__ A, const us* __restrict__ BT,
    const us* __restrict__ bias, void* __restrict__ out,
    int M, int N, int K,
    const us* __restrict__ gate,
    const void* __restrict__ res0, const void* __restrict__ res1,
    const int* __restrict__ oflags) {
  __shared__ __attribute__((aligned(16))) us As[2][128 * 32];
  __shared__ __attribute__((aligned(16))) us Bs[2][128 * 32];
  const int m0 = blockIdx.x * 128, n0 = blockIdx.y * 128;
  const int t = threadIdx.x;
  const int wave = t >> 6, lane = t & 63;
  const int wm = (wave >> 1) * 64, wn = (wave & 1) * 64;
  const int l16 = lane & 15, quad = lane >> 4;
  f32x4 acc[4][4] = {};

  const int lr = lane >> 2, lc = (lane & 3) * 8;
  const us* gA = A + (size_t)(m0 + wave * 32 + lr) * K + lc;
  const us* gB = BT + (size_t)(n0 + wave * 32 + lr) * K + lc;
  const int wo = wave * 1024;

#define STAGE_BT(buf, k)                                    \
  { us* pA = &As[buf][wo]; us* pB = &Bs[buf][wo];           \
    gl2lds16(gA + (k), pA);                                 \
    gl2lds16(gA + (size_t)16 * K + (k), pA + 512);          \
    gl2lds16(gB + (k), pB);                                 \
    gl2lds16(gB + (size_t)16 * K + (k), pB + 512); }

  STAGE_BT(0, 0);
  STAGE_BT(1, 32);
  const int NK = K >> 5;
  int cur = 0;
  for (int i = 0; i < NK - 1; ++i) {
    asm volatile("s_waitcnt vmcnt(4)\n\ts_barrier" ::: "memory");
    bf16x8 af[4], bfv[4];
#pragma unroll
    for (int x = 0; x < 4; ++x) af[x] = *(const bf16x8*)(const void*)&As[cur][(wm + x * 16 + l16) * 32 + quad * 8];
#pragma unroll
    for (int j = 0; j < 4; ++j) bfv[j] = *(const bf16x8*)(const void*)&Bs[cur][(wn + j * 16 + l16) * 32 + quad * 8];
    asm volatile("s_waitcnt lgkmcnt(0)\n\ts_barrier" ::: "memory");
    if (i + 2 < NK) STAGE_BT(cur, (i + 2) * 32);
#pragma unroll
    for (int x = 0; x < 4; ++x)
#pragma unroll
      for (int j = 0; j < 4; ++j)
        acc[x][j] = __builtin_amdgcn_mfma_f32_16x16x32_bf16(af[x], bfv[j], acc[x][j], 0, 0, 0);
    cur ^= 1;
  }
  asm volatile("s_waitcnt vmcnt(0)\n\ts_barrier" ::: "memory");
  {
    bf16x8 af[4], bfv[4];
#pragma unroll
    for (int x = 0; x < 4; ++x) af[x] = *(const bf16x8*)(const void*)&As[cur][(wm + x * 16 + l16) * 32 + quad * 8];
#pragma unroll
    for (int j = 0; j < 4; ++j) bfv[j] = *(const bf16x8*)(const void*)&Bs[cur][(wn + j * 16 + l16) * 32 + quad * 8];
#pragma unroll
    for (int x = 0; x < 4; ++x)
#pragma unroll
      for (int j = 0; j < 4; ++j)
        acc[x][j] = __builtin_amdgcn_mfma_f32_16x16x32_bf16(af[x], bfv[j], acc[x][j], 0, 0, 0);
  }
#undef STAGE_BT

#pragma unroll
  for (int i = 0; i < 4; ++i) {
    const int gm = m0 + wm + i * 16 + quad * 4;
#pragma unroll
    for (int j = 0; j < 4; ++j) {
      const int gn = n0 + wn + j * 16 + l16;
      const float bv = b2f(bias[gn]);
#pragma unroll
      for (int r = 0; r < 4; ++r)
        gemm_epi<EPI>(acc[i][j][r] + bv, gm + r, gn, N, out, gate, res0, res1, oflags);
    }
  }
}

// 128x64-tile variant for N=1024-class GEMMs (2x grid vs 128x128).
template <int EPI>
__global__ __launch_bounds__(256) void gemm_bt64(
    const us* __restrict__ A, const us* __restrict__ BT,
    const us* __restrict__ bias, void* __restrict__ out,
    int M, int N, int K,
    const us* __restrict__ gate,
    const void* __restrict__ res0, const void* __restrict__ res1,
    const int* __restrict__ oflags) {
  __shared__ __attribute__((aligned(16))) us As[2][128 * 32];
  __shared__ __attribute__((aligned(16))) us Bs[2][64 * 32];
  const int m0 = blockIdx.x * 128, n0 = blockIdx.y * 64;
  const int t = threadIdx.x;
  const int wave = t >> 6, lane = t & 63;
  const int wm = (wave >> 1) * 64, wn = (wave & 1) * 32;
  const int l16 = lane & 15, quad = lane >> 4;
  f32x4 acc[4][2] = {};

  const int lr = lane >> 2, lc = (lane & 3) * 8;
  const us* gA = A + (size_t)(m0 + wave * 32 + lr) * K + lc;
  const us* gB = BT + (size_t)(n0 + wave * 16 + lr) * K + lc;
  const int woA = wave * 1024, woB = wave * 512;

#define STAGE_BT64(buf, k)                                  \
  { us* pA = &As[buf][woA];                                 \
    gl2lds16(gA + (k), pA);                                 \
    gl2lds16(gA + (size_t)16 * K + (k), pA + 512);          \
    gl2lds16(gB + (k), &Bs[buf][woB]); }

  STAGE_BT64(0, 0);
  STAGE_BT64(1, 32);
  const int NK = K >> 5;
  int cur = 0;
  for (int i = 0; i < NK - 1; ++i) {
    asm volatile("s_waitcnt vmcnt(3)\n\ts_barrier" ::: "memory");
    bf16x8 af[4], bfv[2];
#pragma unroll
    for (int x = 0; x < 4; ++x) af[x] = *(const bf16x8*)(const void*)&As[cur][(wm + x * 16 + l16) * 32 + quad * 8];
#pragma unroll
    for (int j = 0; j < 2; ++j) bfv[j] = *(const bf16x8*)(const void*)&Bs[cur][(wn + j * 16 + l16) * 32 + quad * 8];
    asm volatile("s_waitcnt lgkmcnt(0)\n\ts_barrier" ::: "memory");
    if (i + 2 < NK) STAGE_BT64(cur, (i + 2) * 32);
#pragma unroll
    for (int x = 0; x < 4; ++x)
#pragma unroll
      for (int j = 0; j < 2; ++j)
        acc[x][j] = __builtin_amdgcn_mfma_f32_16x16x32_bf16(af[x], bfv[j], acc[x][j], 0, 0, 0);
    cur ^= 1;
  }
  asm volatile("s_waitcnt vmcnt(0)\n\ts_barrier" ::: "memory");
  {
    bf16x8 af[4], bfv[2];
#pragma unroll
    for (int x = 0; x < 4; ++x) af[x] = *(const bf16x8*)(const void*)&As[cur][(wm + x * 16 + l16) * 32 + quad * 8];
#pragma unroll
    for (int j = 0; j < 2; ++j) bfv[j] = *(const bf16x8*)(const void*)&Bs[cur][(wn + j * 16 + l16) * 32 + quad * 8];
#pragma unroll
    for (int x = 0; x < 4; ++x)
#pragma unroll
      for (int j = 0; j < 2; ++j)
        acc[x][j] = __builtin_amdgcn_mfma_f32_16x16x32_bf16(af[x], bfv[j], acc[x][j], 0, 0, 0);
  }
#undef STAGE_BT64

#pragma unroll
  for (int i = 0; i < 4; ++i) {
    const int gm = m0 + wm + i * 16 + quad * 4;
#pragma unroll
    for (int j = 0; j < 2; ++j) {
      const int gn = n0 + wn + j * 16 + l16;
      const float bv = b2f(bias[gn]);
#pragma unroll
      for (int r = 0; r < 4; ++r)
        gemm_epi<EPI>(acc[i][j][r] + bv, gm + r, gn, N, out, gate, res0, res1, oflags);
    }
  }
}

// ---------------------------------------------------------------------------
// MFMA flash attention with async gl2lds K/V double-buffer pipeline.
// K/V tiles live in LINEAR [64][64] LDS (gl2lds requires lane-linear dst);
// bank conflicts fixed by XOR-swizzling the per-lane GLOBAL source column
// (col ^= (row&7)*8) and applying the same XOR on the read side (m173).
// One {vmcnt(0); s_barrier} per round; next tile's stage issued before the
// compute so its latency hides under QK+softmax+PV. Safety: all K/V ds_reads
// feed this round's MFMAs (compiler lgkm-waits), so they are drained before
// barrier arrival -> overwriting the other buffer after the barrier is safe.
// LDS: 2*8K (K) + 2*8K (V) + 9K (P) = 41 KB.
// ---------------------------------------------------------------------------
struct AttnState { float m[4], l[4]; f32x4 o[4]; };

DEVI void st_init(AttnState& s) {
#pragma unroll
  for (int r = 0; r < 4; ++r) { s.m[r] = NEGINF; s.l[r] = 0.f; s.o[r] = f32x4{}; }
}

// Wave wv stages its 16 rows of a 64x64 tile via 2 gl2lds (1KB each), with
// source-column swizzle. lds layout: row-major [64][64], row = chunk*8+lane>>3,
// col = (lane&7)*8; data at LDS col c8 comes from global col c8^((row&7)*8).
DEVI void stage_gl(us* __restrict__ lds, const us* __restrict__ gsrc,
                   int strideUs, int wv, int lane) {
  const int rb = lane >> 3, c8 = (lane & 7) * 8;
  const int swz = rb * 8;  // (row & 7) * 8 == rb * 8 for both chunks
#pragma unroll
  for (int k = 0; k < 2; ++k) {
    const int row = wv * 16 + k * 8 + rb;
    gl2lds16(gsrc + (size_t)row * strideUs + (c8 ^ swz), lds + (wv * 2 + k) * 512);
  }
}

template <bool MASKED>
DEVI void attn_round(const us* __restrict__ Kb, const us* __restrict__ Vb,
                     us* __restrict__ Pb, const ull* mrow,
                     bf16x8 aq0, bf16x8 aq1, AttnState& st,
                     int wv, int l16, int quad) {
  f32x4 s[4];
  __builtin_amdgcn_s_setprio(1);
#pragma unroll
  for (int j = 0; j < 4; ++j) {
    const int row = j * 16 + l16;
    const int sw = (row & 7) * 8;
    bf16x8 bk0 = *(const bf16x8*)(const void*)&Kb[row * 64 + ((quad * 8) ^ sw)];
    bf16x8 bk1 = *(const bf16x8*)(const void*)&Kb[row * 64 + ((32 + quad * 8) ^ sw)];
    f32x4 z = {};
    z = __builtin_amdgcn_mfma_f32_16x16x32_bf16(aq0, bk0, z, 0, 0, 0);
    z = __builtin_amdgcn_mfma_f32_16x16x32_bf16(aq1, bk1, z, 0, 0, 0);
    s[j] = z;
  }
  __builtin_amdgcn_s_setprio(0);
  const float CE = 0.18033688011112042f;  // 0.125 * log2(e)
#pragma unroll
  for (int r = 0; r < 4; ++r) {
    float mx = fmaxf(fmaxf(s[0][r], s[1][r]), fmaxf(s[2][r], s[3][r]));
#pragma unroll
    for (int o2 = 8; o2; o2 >>= 1) mx = fmaxf(mx, __shfl_xor(mx, o2));
    const float mn = fmaxf(st.m[r], mx);
    const float alpha = exp2f((st.m[r] - mn) * CE);  // -inf start -> 0
    const float mnC = mn * CE;
    float rs = 0.f;
#pragma unroll
    for (int j = 0; j < 4; ++j) {
      float p = exp2f(__builtin_fmaf(s[j][r], CE, -mnC));
      if constexpr (MASKED) p = ((mrow[r] >> (j * 16 + l16)) & 1ull) ? p : 0.f;
      rs += p;
      ((__bf16*)Pb)[(wv * 16 + quad * 4 + r) * 72 + j * 16 + l16] = (__bf16)p;
    }
#pragma unroll
    for (int o2 = 8; o2; o2 >>= 1) rs += __shfl_xor(rs, o2);
    st.m[r] = mn;
    st.l[r] = st.l[r] * alpha + rs;
#pragma unroll
    for (int jd = 0; jd < 4; ++jd) st.o[jd][r] *= alpha;
  }
  bf16x8 ap0 = *(const bf16x8*)(const void*)&Pb[(wv * 16 + l16) * 72 + quad * 8];
  bf16x8 ap1 = *(const bf16x8*)(const void*)&Pb[(wv * 16 + l16) * 72 + 32 + quad * 8];
  __builtin_amdgcn_s_setprio(1);
#pragma unroll
  for (int jd = 0; jd < 4; ++jd) {
    const int row = jd * 16 + l16;
    const int sw = (row & 7) * 8;
    bf16x8 v0 = *(const bf16x8*)(const void*)&Vb[row * 64 + ((quad * 8) ^ sw)];
    bf16x8 v1 = *(const bf16x8*)(const void*)&Vb[row * 64 + ((32 + quad * 8) ^ sw)];
    st.o[jd] = __builtin_amdgcn_mfma_f32_16x16x32_bf16(ap0, v0, st.o[jd], 0, 0, 0);
    st.o[jd] = __builtin_amdgcn_mfma_f32_16x16x32_bf16(ap1, v1, st.o[jd], 0, 0, 0);
  }
  __builtin_amdgcn_s_setprio(0);
}

DEVI void attn_write(us* __restrict__ y, const AttnState& st, int rowAbs,
                     int h, int l16, int quad) {
#pragma unroll
  for (int r = 0; r < 4; ++r) {
    const float inv = (st.l[r] > 0.f) ? 1.f / st.l[r] : 0.f;
#pragma unroll
    for (int jd = 0; jd < 4; ++jd)
      y[(size_t)(rowAbs + quad * 4 + r) * 1024 + h * 64 + jd * 16 + l16] =
          f2b(st.o[jd][r] * inv);
  }
}

// Cross: 256 keys = 4 rounds; no masks.
__global__ __launch_bounds__(256) void cross_attn_mfma(
    const us* __restrict__ q, const us* __restrict__ kv,
    const us* __restrict__ vT, us* __restrict__ y) {
  __shared__ __attribute__((aligned(16))) us Kb[2][64 * 64];
  __shared__ __attribute__((aligned(16))) us Vb[2][64 * 64];
  __shared__ __attribute__((aligned(16))) us Pb[64 * 72];
  const int bid = blockIdx.x;
  const int xcd = bid & 7, tmp = bid >> 3;
  const int tt = tmp & 15, gq = tmp >> 4;
  const int g = gq * 8 + xcd;          // (st,b,h) group
  const int strm = g >> 5, b = (g >> 4) & 1, h = g & 15;
  const int t = threadIdx.x, wv = t >> 6, lane = t & 63;
  const int l16 = lane & 15, quad = lane >> 4;
  const int rowbase = strm * 2048 + b * 1024 + tt * 64 + wv * 16;
  const us* qp = q + (size_t)(rowbase + l16) * 1024 + h * 64 + quad * 8;
  bf16x8 aq0 = *(const bf16x8*)(qp);
  bf16x8 aq1 = *(const bf16x8*)(qp + 32);
  const us* kb = kv + (size_t)b * (256 * 2048) + h * 64;
  const us* vb = vT + (size_t)(b * 16 + h) * (64 * 256);
  AttnState st; st_init(st);
  __syncthreads();
  stage_gl(Kb[0], kb, 2048, wv, lane);
  stage_gl(Vb[0], vb, 256, wv, lane);
  int cur = 0;
  for (int rnd = 0; rnd < 4; ++rnd) {
    asm volatile("s_waitcnt vmcnt(0)\n\ts_barrier" ::: "memory");
    if (rnd < 3) {
      stage_gl(Kb[cur ^ 1], kb + (size_t)(rnd + 1) * 64 * 2048, 2048, wv, lane);
      stage_gl(Vb[cur ^ 1], vb + (rnd + 1) * 64, 256, wv, lane);
    }
    attn_round<false>(Kb[cur], Vb[cur], Pb, nullptr, aq0, aq1, st, wv, l16, quad);
    cur ^= 1;
  }
  attn_write(y, st, rowbase, h, l16, quad);
}

// Star: causal+dep; only the diagonal chunk needs the causal bits.
DEVI void star_body(us (*Kb)[4096], us (*Vb)[4096], us* Pb,
                    const us* qkv, const us* vT,
                    const ull* depb, us* y, int b, int h, int tt, int t) {
  const int wv = t >> 6, lane = t & 63;
  const int l16 = lane & 15, quad = lane >> 4;
  const int t0 = tt * 64;
  const int rowbase = b * 1024 + t0 + wv * 16;
  const us* qp = qkv + (size_t)(rowbase + l16) * 3072 + h * 64 + quad * 8;
  bf16x8 aq0 = *(const bf16x8*)(qp);
  bf16x8 aq1 = *(const bf16x8*)(qp + 32);
  const us* kb = qkv + (size_t)(b * 1024) * 3072 + 1024 + h * 64;
  const us* vb = vT + (size_t)(b * 16 + h) * 65536;
  AttnState st; st_init(st);
  ull mrow[4];
  __syncthreads();
  stage_gl(Kb[0], kb, 3072, wv, lane);
  stage_gl(Vb[0], vb, 1024, wv, lane);
  int cur = 0;
  for (int ck = 0; ck <= tt; ++ck) {
    asm volatile("s_waitcnt vmcnt(0)\n\ts_barrier" ::: "memory");
    if (ck < tt) {
      stage_gl(Kb[cur ^ 1], kb + (size_t)(ck + 1) * 64 * 3072, 3072, wv, lane);
      stage_gl(Vb[cur ^ 1], vb + (ck + 1) * 64, 1024, wv, lane);
    }
#pragma unroll
    for (int r = 0; r < 4; ++r) {
      ull d = depb[(size_t)(rowbase + quad * 4 + r) * 16 + ck];
      if (ck == tt) {
        const int idx = wv * 16 + quad * 4 + r;  // trow - s0 (t0 == s0 here)
        d &= (2ull << idx) - 1ull;               // bits 0..idx (idx=63 -> ~0)
      }
      mrow[r] = d;
    }
    attn_round<true>(Kb[cur], Vb[cur], Pb, mrow, aq0, aq1, st, wv, l16, quad);
    cur ^= 1;
  }
  attn_write(y, st, rowbase, h, l16, quad);
}

// Hat: slot-mask walk (slot = 2*ck + part) with one-round stage lookahead.
DEVI void hat_body(us (*Kb)[4096], us (*Vb)[4096], us* Pb,
                   const us* qkv, const us* vsT, const us* vhT,
                   const ull* starb, const ull* hatb, const ull* depb,
                   const int* bflags, us* y, int b, int h, int tt, int t) {
  const int wv = t >> 6, lane = t & 63;
  const int l16 = lane & 15, quad = lane >> 4;
  const int t0 = tt * 64;
  const int rowbase = b * 1024 + t0 + wv * 16;
  const us* qp = qkv + (size_t)(2048 + rowbase + l16) * 3072 + h * 64 + quad * 8;
  bf16x8 aq0 = *(const bf16x8*)(qp);
  bf16x8 aq1 = *(const bf16x8*)(qp + 32);
  const us* ksb = qkv + (size_t)(b * 1024) * 3072 + 1024 + h * 64;
  const us* khb = qkv + (size_t)(2048 + b * 1024) * 3072 + 1024 + h * 64;
  const us* vsb = vsT + (size_t)(b * 16 + h) * 65536;
  const us* vhb = vhT + (size_t)(b * 16 + h) * 65536;
  AttnState st; st_init(st);
  unsigned mask = 0;
  for (int ck = 0; ck < 16; ++ck) {
    int f = bflags[(b * 16 + tt) * 16 + ck];
    mask |= (unsigned)(f & 3) << (2 * ck);
  }
  if (mask) {
    int slot = (int)__builtin_ctz(mask);
    unsigned rem = mask & (mask - 1);
    __syncthreads();
    {
      const int ck = slot >> 1, part = slot & 1;
      stage_gl(Kb[0], (part ? khb : ksb) + (size_t)ck * 64 * 3072, 3072, wv, lane);
      stage_gl(Vb[0], (part ? vhb : vsb) + ck * 64, 1024, wv, lane);
    }
    int cur = 0;
    for (;;) {
      asm volatile("s_waitcnt vmcnt(0)\n\ts_barrier" ::: "memory");
      const int ck = slot >> 1, part = slot & 1;
      int nslot = -1;
      if (rem) {
        nslot = (int)__builtin_ctz(rem);
        rem &= rem - 1;
        const int nck = nslot >> 1, npart = nslot & 1;
        stage_gl(Kb[cur ^ 1], (npart ? khb : ksb) + (size_t)nck * 64 * 3072, 3072, wv, lane);
        stage_gl(Vb[cur ^ 1], (npart ? vhb : vsb) + nck * 64, 1024, wv, lane);
      }
      ull mrow[4];
#pragma unroll
      for (int r = 0; r < 4; ++r) {
        const size_t mi = (size_t)(rowbase + quad * 4 + r) * 16 + ck;
        mrow[r] = (part ? hatb[mi] : starb[mi]) & depb[mi];
      }
      attn_round<true>(Kb[cur], Vb[cur], Pb, mrow, aq0, aq1, st, wv, l16, quad);
      if (nslot < 0) break;
      slot = nslot;
      cur ^= 1;
    }
  }
  attn_write(y, st, 2048 + rowbase, h, l16, quad);
}

// XCD-swizzled merged self-attention with complementary-pair load balance.
__global__ __launch_bounds__(256) void self_attn_mfma(
    const us* __restrict__ qkv,
    const us* __restrict__ vstT, const us* __restrict__ vhtT,
    const ull* __restrict__ sbits, const ull* __restrict__ hbits,
    const ull* __restrict__ dbits, const int* __restrict__ bflags,
    us* __restrict__ y) {
  __shared__ __attribute__((aligned(16))) us Kb[2][64 * 64];
  __shared__ __attribute__((aligned(16))) us Vb[2][64 * 64];
  __shared__ __attribute__((aligned(16))) us Pb[64 * 72];
  const int bid = blockIdx.x;
  const int xcd = bid & 7, tmp = bid >> 3;
  const int pr = tmp & 7, gq = tmp >> 3;
  const int g = gq * 8 + xcd;
  const int ttA = pr, ttB = 15 - pr;
  const int t = threadIdx.x;
  if (g < 32) {
    star_body(Kb, Vb, Pb, qkv, vstT, dbits, y, g >> 4, g & 15, ttA, t);
    star_body(Kb, Vb, Pb, qkv, vstT, dbits, y, g >> 4, g & 15, ttB, t);
  } else {
    const int g2 = g - 32;
    hat_body(Kb, Vb, Pb, qkv, vstT, vhtT, sbits, hbits, dbits, bflags,
             y, g2 >> 4, g2 & 15, ttA, t);
    hat_body(Kb, Vb, Pb, qkv, vstT, vhtT, sbits, hbits, dbits, bflags,
             y, g2 >> 4, g2 & 15, ttB, t);
  }
}

// ---------------------------------------------------------------------------
extern "C" void kernel_launch(void* const* d_in, const int* in_sizes, int n_in,
                              void* d_out, int out_size, void* d_ws, size_t ws_size,
                              hipStream_t stream) {
  const void* xs = d_in[0];
  const void* xh = d_in[1];
  const void* cc = d_in[2];
  const void* mstar = d_in[3];
  const void* mhat = d_in[4];
  const void* mdep = d_in[5];
  const void* ng = d_in[6];
  const void* nb = d_in[7];
  const void* Wq = d_in[8];
  const void* bq = d_in[9];
  const void* Wkv = d_in[10];
  const void* bkv = d_in[11];
  const void* Wco = d_in[12];
  const void* bco = d_in[13];
  const void* Wada = d_in[14];
  const void* bada = d_in[15];
  const void* Wqkv = d_in[16];
  const void* bqkv = d_in[17];
  const void* Wo = d_in[18];
  const void* bo = d_in[19];
  const void* W1 = d_in[20];
  const void* b1 = d_in[21];
  const void* W2 = d_in[22];
  const void* b2 = d_in[23];
  (void)in_sizes; (void)n_in; (void)out_size; (void)ws_size;

  char* ws = (char*)d_ws;
  size_t off = 0;
  auto alloc = [&](size_t bytes) -> char* {
    char* p = ws + off;
    off += (bytes + 255) & ~(size_t)255;
    return p;
  };
  int* flags = (int*)alloc(256);
  int* bflags = (int*)alloc(512 * 4);
  us* smallb = (us*)alloc(21504 * 2);
  us* ngb = smallb, *nbb = smallb + 1024, *bqb = smallb + 2048,
      *bkvb = smallb + 3072, *bcob = smallb + 5120, *badab = smallb + 6144,
      *bqkvb = smallb + 12288, *bob = smallb + 15360, *b1b = smallb + 16384,
      *b2b = smallb + 20480;
  us* WqT = (us*)alloc(1048576ull * 2);
  us* WkvT = (us*)alloc(2097152ull * 2);
  us* WcoT = (us*)alloc(1048576ull * 2);
  us* WadaT = (us*)alloc(6291456ull * 2);
  us* WqkvT = (us*)alloc(3145728ull * 2);
  us* WoT = (us*)alloc(1048576ull * 2);
  us* W1T = (us*)alloc(4194304ull * 2);
  us* W2T = (us*)alloc(4194304ull * 2);
  us* xn = (us*)alloc(4194304ull * 2);
  us* qb = (us*)alloc(4194304ull * 2);
  us* kvb = (us*)alloc(1048576ull * 2);
  us* gada = (us*)alloc(25165824ull * 2);
  us* msb = (us*)alloc(4194304ull * 2);
  us* qkvb = (us*)alloc(12582912ull * 2);
  float* x1 = (float*)alloc(4194304ull * 4);
  us* hid = (us*)alloc(16777216ull * 2);
  ull* mb = (ull*)alloc(3ull * 32768 * 8);
  us* kvT = (us*)alloc(524288ull * 2);
  us* vstT = (us*)alloc(2097152ull * 2);
  us* vhtT = (us*)alloc(2097152ull * 2);

  ull* sbits = mb;
  ull* hbits = mb + 32768;
  ull* dbits = mb + 65536;
  us* ccb = hid;              // dead before hid written
  us* lnx = hid + 1048576;    // dead before hid written
  us* yca = xn;
  us* silub = qb;
  us* yat = msb;

  dim3 blk(256);
  detect_flags<<<1, blk, 0, stream>>>((const unsigned int*)xs, (const unsigned int*)mdep, flags);

  cvt_bf16<<<512, blk, 0, stream>>>(cc, ccb, 524288, flags);
  P10 ps10; ps10.p[0] = ng; ps10.p[1] = nb; ps10.p[2] = bq; ps10.p[3] = bkv;
  ps10.p[4] = bco; ps10.p[5] = bada; ps10.p[6] = bqkv; ps10.p[7] = bo;
  ps10.p[8] = b1; ps10.p[9] = b2;
  cvt_small<<<84, blk, 0, stream>>>(ps10, smallb, flags);

  transpose_cvt64<<<dim3(16, 16), blk, 0, stream>>>(Wq, WqT, 1024, 1024, flags);
  transpose_cvt64<<<dim3(16, 32), blk, 0, stream>>>(Wkv, WkvT, 1024, 2048, flags);
  transpose_cvt64<<<dim3(16, 16), blk, 0, stream>>>(Wco, WcoT, 1024, 1024, flags);
  transpose_cvt64<<<dim3(16, 96), blk, 0, stream>>>(Wada, WadaT, 1024, 6144, flags);
  transpose_cvt64<<<dim3(16, 48), blk, 0, stream>>>(Wqkv, WqkvT, 1024, 3072, flags);
  transpose_cvt64<<<dim3(16, 16), blk, 0, stream>>>(Wo, WoT, 1024, 1024, flags);
  transpose_cvt64<<<dim3(16, 64), blk, 0, stream>>>(W1, W1T, 1024, 4096, flags);
  transpose_cvt64<<<dim3(64, 16), blk, 0, stream>>>(W2, W2T, 4096, 1024, flags);

  P3 ps3; ps3.p[0] = mstar; ps3.p[1] = mhat; ps3.p[2] = mdep;
  pack_mask3<<<dim3(512, 3), blk, 0, stream>>>(ps3, mb, flags);
  hat_blockflags<<<32, blk, 0, stream>>>(sbits, hbits, bflags);

  ln_affine<<<4096, blk, 0, stream>>>(xs, xh, ngb, nbb, lnx, xn, flags);
  gemm_bt64<EPI_BF16><<<dim3(32, 16), blk, 0, stream>>>(xn, WqT, bqb, qb, 4096, 1024, 1024, nullptr, nullptr, nullptr, nullptr);
  gemm_bt64<EPI_BF16><<<dim3(4, 32), blk, 0, stream>>>(ccb, WkvT, bkvb, kvb, 512, 2048, 1024, nullptr, nullptr, nullptr, nullptr);
  vtrans<<<dim3(4, 32), blk, 0, stream>>>(kvb, kvT, 256, 2048, 1024, 0);
  cross_attn_mfma<<<1024, blk, 0, stream>>>(qb, kvb, kvT, yca);
  gemm_bt64<EPI_SILU><<<dim3(32, 16), blk, 0, stream>>>(yca, WcoT, bcob, silub, 4096, 1024, 1024, nullptr, nullptr, nullptr, nullptr);
  gemm_bt<EPI_BF16><<<dim3(32, 48), blk, 0, stream>>>(silub, WadaT, badab, gada, 4096, 6144, 1024, nullptr, nullptr, nullptr, nullptr);
  mod_ms<<<4096, blk, 0, stream>>>(lnx, gada, msb);
  gemm_bt<EPI_BF16><<<dim3(32, 24), blk, 0, stream>>>(msb, WqkvT, bqkvb, qkvb, 4096, 3072, 1024, nullptr, nullptr, nullptr, nullptr);
  vtrans_qkv<<<dim3(16, 32, 2), blk, 0, stream>>>(qkvb, vstT, vhtT);
  self_attn_mfma<<<512, blk, 0, stream>>>(qkvb, vstT, vhtT, sbits, hbits, dbits, bflags, yat);
  gemm_bt64<EPI_GATE_XRES><<<dim3(32, 16), blk, 0, stream>>>(yat, WoT, bob, x1, 4096, 1024, 1024, gada + 2048, xs, xh, flags);
  ln_mod<<<4096, blk, 0, stream>>>(x1, gada, msb);
  gemm_bt<EPI_GELU><<<dim3(32, 32), blk, 0, stream>>>(msb, W1T, b1b, hid, 4096, 4096, 1024, nullptr, nullptr, nullptr, nullptr);
  gemm_bt64<EPI_GATE_OUT><<<dim3(32, 16), blk, 0, stream>>>(hid, W2T, b2b, d_out, 4096, 1024, 4096, gada + 5120, x1, nullptr, flags);
}

// Round 11
// 622.466 us; speedup vs baseline: 1.1697x; 1.1697x over previous
//
#include <hip/hip_runtime.h>
#include <hip/hip_bf16.h>
#include <stdint.h>

#define DEVI __device__ __forceinline__

typedef __bf16 bf16x8 __attribute__((ext_vector_type(8)));
typedef float f32x4 __attribute__((ext_vector_type(4)));
typedef unsigned short us;
typedef unsigned long long ull;

DEVI float b2f(us u) { union { unsigned int i; float f; } v; v.i = ((unsigned int)u) << 16; return v.f; }
DEVI us f2b(float f) {
  union { unsigned int i; float f; } v; v.f = f;
  unsigned int r = (v.i + 0x7fffu + ((v.i >> 16) & 1u)) >> 16;
  return (us)r;
}

#define NEGINF (-__builtin_inff())

DEVI void gl2lds16(const us* g, us* l) {
  __builtin_amdgcn_global_load_lds(
      (const __attribute__((address_space(1))) unsigned int*)g,
      (__attribute__((address_space(3))) unsigned int*)l, 16, 0, 0);
}

// ---------------------------------------------------------------------------
// Runtime dtype detection. flags[0]: f32 inputs; flags[1]: byte-packed masks.
// ---------------------------------------------------------------------------
__global__ __launch_bounds__(256) void detect_flags(
    const unsigned int* __restrict__ xw, const unsigned int* __restrict__ mw,
    int* __restrict__ flags) {
  const int t = threadIdx.x;
  int cnt = 0, big = 0;
  for (int i = t; i < 4096; i += 256) {
    unsigned int w = xw[i];
    us lo = (us)(w & 0xffffu);
    float a = fabsf(b2f(lo));
    cnt += ((lo == 0) || (a >= 1e-8f && a <= 256.f)) ? 1 : 0;
    big |= (mw[i] > 1u) ? 1 : 0;
  }
  for (int o = 32; o; o >>= 1) { cnt += __shfl_down(cnt, o); big |= __shfl_down(big, o); }
  __shared__ int sc[4], sb[4];
  if ((t & 63) == 0) { sc[t >> 6] = cnt; sb[t >> 6] = big; }
  __syncthreads();
  if (t == 0) {
    flags[0] = (sc[0] + sc[1] + sc[2] + sc[3] < 2048) ? 1 : 0;
    flags[1] = (sb[0] | sb[1] | sb[2] | sb[3]);
  }
}

__global__ __launch_bounds__(256) void cvt_bf16(
    const void* __restrict__ src, us* __restrict__ dst, int n,
    const int* __restrict__ flags) {
  const int f32mode = flags[0];
  int idx = (blockIdx.x * 256 + threadIdx.x) * 4;
  if (idx >= n) return;
  if (f32mode) {
    const float* s = (const float*)src;
    float4 v = *(const float4*)(s + idx);
    dst[idx] = f2b(v.x); dst[idx + 1] = f2b(v.y);
    dst[idx + 2] = f2b(v.z); dst[idx + 3] = f2b(v.w);
  } else {
    *(uint2*)(dst + idx) = *(const uint2*)((const us*)src + idx);
  }
}

struct P10 { const void* p[10]; };
__global__ __launch_bounds__(256) void cvt_small(P10 ps, us* __restrict__ dst,
                                                 const int* __restrict__ flags) {
  const int offs[11] = {0, 1024, 2048, 3072, 5120, 6144, 12288, 15360, 16384, 20480, 21504};
  int idx = blockIdx.x * 256 + threadIdx.x;
  if (idx >= 21504) return;
  int seg = 0;
#pragma unroll
  for (int i = 1; i < 10; ++i) seg += (idx >= offs[i]) ? 1 : 0;
  int local = idx - offs[seg];
  float v = flags[0] ? ((const float*)ps.p[seg])[local]
                     : b2f(((const us*)ps.p[seg])[local]);
  dst[idx] = f2b(v);
}

// Vectorized 64x64 convert+transpose: W (K,N) f32/bf16 -> WT (N,K) bf16.
__global__ __launch_bounds__(256) void transpose_cvt64(
    const void* __restrict__ W, us* __restrict__ WT, int K, int N,
    const int* __restrict__ flags) {
  __shared__ __attribute__((aligned(16))) us tile[64 * 72];
  const int f32m = flags[0];
  const int k0 = blockIdx.x * 64, n0 = blockIdx.y * 64;
  const int t = threadIdx.x;
  const int row = t >> 2, colb = (t & 3) * 16;
  const int sw = ((row >> 4) & 3) << 4;
  us tmp[16];
  if (f32m) {
    const float* src = (const float*)W + (size_t)(k0 + row) * N + n0 + colb;
#pragma unroll
    for (int i = 0; i < 16; i += 4) {
      float4 v = *(const float4*)(src + i);
      tmp[i] = f2b(v.x); tmp[i + 1] = f2b(v.y); tmp[i + 2] = f2b(v.z); tmp[i + 3] = f2b(v.w);
    }
  } else {
    const us* src = (const us*)W + (size_t)(k0 + row) * N + n0 + colb;
    *(uint4*)tmp = *(const uint4*)src;
    *(uint4*)(tmp + 8) = *(const uint4*)(src + 8);
  }
  *(uint4*)&tile[row * 72 + (colb ^ sw)] = *(uint4*)tmp;
  *(uint4*)&tile[row * 72 + (colb ^ sw) + 8] = *(uint4*)(tmp + 8);
  __syncthreads();
  const int orow = t >> 2, ocolb = (t & 3) * 16;
  const int pc = (orow & 15) | ((orow & 48) ^ (ocolb & 48));
  us out[16];
#pragma unroll
  for (int i = 0; i < 16; ++i) out[i] = tile[(ocolb + i) * 72 + pc];
  us* dst = WT + (size_t)(n0 + orow) * K + k0 + ocolb;
  *(uint4*)dst = *(uint4*)out;
  *(uint4*)(dst + 8) = *(uint4*)(out + 8);
}

struct P3 { const void* p[3]; };
__global__ __launch_bounds__(256) void pack_mask3(P3 ms, ull* __restrict__ bits,
                                                  const int* __restrict__ flags) {
  const int bytemode = flags[1];
  const void* m = ms.p[blockIdx.y];
  ull* out = bits + (size_t)blockIdx.y * 32768;
  int wv = blockIdx.x * 4 + (threadIdx.x >> 6);
  int lane = threadIdx.x & 63;
  for (int w = 0; w < 16; ++w) {
    int v;
    if (bytemode) v = ((const unsigned char*)m)[(size_t)wv * 1024 + w * 64 + lane];
    else          v = ((const int*)m)[(size_t)wv * 1024 + w * 64 + lane];
    ull b = __ballot(v != 0);
    if (lane == 0) out[(size_t)wv * 16 + w] = b;
  }
}

__global__ __launch_bounds__(256) void hat_blockflags(
    const ull* __restrict__ starb, const ull* __restrict__ hatb, int* __restrict__ bf) {
  const int bt = blockIdx.x;
  const int b = bt >> 4, tt = bt & 15;
  const int t = threadIdx.x, wv = t >> 6, lane = t & 63;
  const int t0 = tt * 64;
  for (int k = 0; k < 4; ++k) {
    int ck = wv * 4 + k;
    ull sw = starb[(size_t)(b * 1024 + t0 + lane) * 16 + ck];
    ull hw = hatb[(size_t)(b * 1024 + t0 + lane) * 16 + ck];
    int f = (__ballot(sw != 0ull) ? 1 : 0) | (__ballot(hw != 0ull) ? 2 : 0);
    if (lane == 0) bf[bt * 16 + ck] = f;
  }
}

// V transpose to [bh][64(d)][T]
__global__ __launch_bounds__(256) void vtrans(
    const us* __restrict__ src, us* __restrict__ dst,
    int T, int stride, int colBase, int rowOff) {
  __shared__ __attribute__((aligned(16))) us tile[64][65];
  const int bh = blockIdx.y, b = bh >> 4, h = bh & 15;
  const int t0 = blockIdx.x * 64;
  const int t = threadIdx.x;
#pragma unroll
  for (int it = 0; it < 2; ++it) {
    int idx = it * 256 + t; int r = idx >> 3, c8 = (idx & 7) * 8;
    uint4 d4 = *(const uint4*)(src + (size_t)(rowOff + b * T + t0 + r) * stride + colBase + h * 64 + c8);
    const us* e = (const us*)&d4;
#pragma unroll
    for (int i = 0; i < 8; ++i) tile[r][c8 + i] = e[i];
  }
  __syncthreads();
#pragma unroll
  for (int it = 0; it < 2; ++it) {
    int idx = it * 256 + t; int d = idx >> 3, c8 = (idx & 7) * 8;
    us tmp[8];
#pragma unroll
    for (int i = 0; i < 8; ++i) tmp[i] = tile[c8 + i][d];
    *(uint4*)(dst + ((size_t)(bh * 64 + d)) * T + t0 + c8) = *(const uint4*)tmp;
  }
}

// Both self-attn V transposes (star z=0, hat z=1) in one launch.
__global__ __launch_bounds__(256) void vtrans_qkv(
    const us* __restrict__ src, us* __restrict__ dst0, us* __restrict__ dst1) {
  __shared__ __attribute__((aligned(16))) us tile[64][65];
  const int z = blockIdx.z;
  us* dst = z ? dst1 : dst0;
  const int rowOff = z ? 2048 : 0;
  const int bh = blockIdx.y, b = bh >> 4, h = bh & 15;
  const int t0 = blockIdx.x * 64;
  const int t = threadIdx.x;
#pragma unroll
  for (int it = 0; it < 2; ++it) {
    int idx = it * 256 + t; int r = idx >> 3, c8 = (idx & 7) * 8;
    uint4 d4 = *(const uint4*)(src + (size_t)(rowOff + b * 1024 + t0 + r) * 3072 + 2048 + h * 64 + c8);
    const us* e = (const us*)&d4;
#pragma unroll
    for (int i = 0; i < 8; ++i) tile[r][c8 + i] = e[i];
  }
  __syncthreads();
#pragma unroll
  for (int it = 0; it < 2; ++it) {
    int idx = it * 256 + t; int d = idx >> 3, c8 = (idx & 7) * 8;
    us tmp[8];
#pragma unroll
    for (int i = 0; i < 8; ++i) tmp[i] = tile[c8 + i][d];
    *(uint4*)(dst + ((size_t)(bh * 64 + d)) * 1024 + t0 + c8) = *(const uint4*)tmp;
  }
}

// ---------------------------------------------------------------------------
// LayerNorm + modulation
// ---------------------------------------------------------------------------
__global__ __launch_bounds__(256) void ln_affine(
    const void* __restrict__ xs, const void* __restrict__ xh,
    const us* __restrict__ gw, const us* __restrict__ bw,
    us* __restrict__ lnx, us* __restrict__ xn, const int* __restrict__ flags) {
  const int f32m = flags[0];
  const int row = blockIdx.x;
  const void* xp = (row < 2048) ? xs : xh;
  const size_t base = (size_t)(row & 2047) * 1024;
  const int t = threadIdx.x;
  float v[4]; float s = 0.f, ss = 0.f;
#pragma unroll
  for (int i = 0; i < 4; ++i) {
    size_t idx = base + i * 256 + t;
    float x = f32m ? ((const float*)xp)[idx] : b2f(((const us*)xp)[idx]);
    v[i] = x; s += x; ss += x * x;
  }
  for (int o = 32; o; o >>= 1) { s += __shfl_down(s, o); ss += __shfl_down(ss, o); }
  __shared__ float red[2][4];
  const int wv = t >> 6, lane = t & 63;
  if (lane == 0) { red[0][wv] = s; red[1][wv] = ss; }
  __syncthreads();
  s = red[0][0] + red[0][1] + red[0][2] + red[0][3];
  ss = red[1][0] + red[1][1] + red[1][2] + red[1][3];
  const float mean = s * (1.f / 1024.f);
  const float var = fmaxf(ss * (1.f / 1024.f) - mean * mean, 0.f);
  const float rstd = rsqrtf(var + 1e-6f);
  const size_t ro = (size_t)row * 1024;
#pragma unroll
  for (int i = 0; i < 4; ++i) {
    int c = i * 256 + t;
    float n = (v[i] - mean) * rstd;
    lnx[ro + c] = f2b(n);
    xn[ro + c] = f2b(n * b2f(gw[c]) + b2f(bw[c]));
  }
}

__global__ __launch_bounds__(256) void mod_ms(
    const us* __restrict__ lnx, const us* __restrict__ gada, us* __restrict__ ms) {
  const size_t idx = ((size_t)blockIdx.x * 256 + threadIdx.x) * 4;
  const int row = (int)(idx >> 10), c = (int)(idx & 1023);
  const size_t gb = (size_t)row * 6144;
#pragma unroll
  for (int i = 0; i < 4; ++i) {
    float sh = b2f(gada[gb + c + i]);
    float sc = b2f(gada[gb + 1024 + c + i]);
    ms[idx + i] = f2b(b2f(lnx[idx + i]) * (1.f + sc) + sh);
  }
}

__global__ __launch_bounds__(256) void ln_mod(
    const float* __restrict__ x1, const us* __restrict__ gada, us* __restrict__ m2) {
  const int row = blockIdx.x;
  const float* xp = x1 + (size_t)row * 1024;
  const int t = threadIdx.x;
  float v[4]; float s = 0.f, ss = 0.f;
#pragma unroll
  for (int i = 0; i < 4; ++i) { float x = xp[i * 256 + t]; v[i] = x; s += x; ss += x * x; }
  for (int o = 32; o; o >>= 1) { s += __shfl_down(s, o); ss += __shfl_down(ss, o); }
  __shared__ float red[2][4];
  const int wv = t >> 6, lane = t & 63;
  if (lane == 0) { red[0][wv] = s; red[1][wv] = ss; }
  __syncthreads();
  s = red[0][0] + red[0][1] + red[0][2] + red[0][3];
  ss = red[1][0] + red[1][1] + red[1][2] + red[1][3];
  const float mean = s * (1.f / 1024.f);
  const float var = fmaxf(ss * (1.f / 1024.f) - mean * mean, 0.f);
  const float rstd = rsqrtf(var + 1e-6f);
  const size_t gb = (size_t)row * 6144;
#pragma unroll
  for (int i = 0; i < 4; ++i) {
    int c = i * 256 + t;
    float n = (v[i] - mean) * rstd;
    float sh = b2f(gada[gb + 3072 + c]);
    float sc = b2f(gada[gb + 4096 + c]);
    m2[(size_t)row * 1024 + c] = f2b(n * (1.f + sc) + sh);
  }
}

// ---------------------------------------------------------------------------
// MFMA GEMM with counted-vmcnt double-buffer pipeline (r6-proven structure).
// ---------------------------------------------------------------------------
enum { EPI_BF16 = 0, EPI_SILU, EPI_GELU, EPI_GATE_XRES, EPI_GATE_OUT };

template <int EPI>
DEVI void gemm_epi(float v, int gmr, int gn, int N, void* out,
                   const us* gate, const void* res0, const void* res1,
                   const int* oflags) {
  const size_t oi = (size_t)gmr * N + gn;
  if constexpr (EPI == EPI_BF16) {
    ((us*)out)[oi] = f2b(v);
  } else if constexpr (EPI == EPI_SILU) {
    ((us*)out)[oi] = f2b(v / (1.f + __expf(-v)));
  } else if constexpr (EPI == EPI_GELU) {
    float u = 0.7978845608028654f * (v + 0.044715f * v * v * v);
    float th = 1.f - 2.f / (__expf(2.f * u) + 1.f);
    ((us*)out)[oi] = f2b(0.5f * v * (1.f + th));
  } else if constexpr (EPI == EPI_GATE_XRES) {
    float g = b2f(gate[(size_t)gmr * 6144 + gn]);
    const void* xr = (gmr < 2048) ? res0 : res1;
    size_t xi = (size_t)(gmr & 2047) * 1024 + gn;
    float x = oflags[0] ? ((const float*)xr)[xi] : b2f(((const us*)xr)[xi]);
    ((float*)out)[oi] = x + g * v;
  } else {
    float g = b2f(gate[(size_t)gmr * 6144 + gn]);
    float x = ((const float*)res0)[oi];
    float r2 = x + g * v;
    if (oflags[0]) ((float*)out)[oi] = r2;
    else ((us*)out)[oi] = f2b(r2);
  }
}

template <int EPI>
__global__ __launch_bounds__(256) void gemm_bt(
    const us* __restrict__ A, const us* __restrict__ BT,
    const us* __restrict__ bias, void* __restrict__ out,
    int M, int N, int K,
    const us* __restrict__ gate,
    const void* __restrict__ res0, const void* __restrict__ res1,
    const int* __restrict__ oflags) {
  __shared__ __attribute__((aligned(16))) us As[2][128 * 32];
  __shared__ __attribute__((aligned(16))) us Bs[2][128 * 32];
  const int m0 = blockIdx.x * 128, n0 = blockIdx.y * 128;
  const int t = threadIdx.x;
  const int wave = t >> 6, lane = t & 63;
  const int wm = (wave >> 1) * 64, wn = (wave & 1) * 64;
  const int l16 = lane & 15, quad = lane >> 4;
  f32x4 acc[4][4] = {};

  const int lr = lane >> 2, lc = (lane & 3) * 8;
  const us* gA = A + (size_t)(m0 + wave * 32 + lr) * K + lc;
  const us* gB = BT + (size_t)(n0 + wave * 32 + lr) * K + lc;
  const int wo = wave * 1024;

#define STAGE_BT(buf, k)                                    \
  { us* pA = &As[buf][wo]; us* pB = &Bs[buf][wo];           \
    gl2lds16(gA + (k), pA);                                 \
    gl2lds16(gA + (size_t)16 * K + (k), pA + 512);          \
    gl2lds16(gB + (k), pB);                                 \
    gl2lds16(gB + (size_t)16 * K + (k), pB + 512); }

  STAGE_BT(0, 0);
  STAGE_BT(1, 32);
  const int NK = K >> 5;
  int cur = 0;
  for (int i = 0; i < NK - 1; ++i) {
    asm volatile("s_waitcnt vmcnt(4)\n\ts_barrier" ::: "memory");
    bf16x8 af[4], bfv[4];
#pragma unroll
    for (int x = 0; x < 4; ++x) af[x] = *(const bf16x8*)(const void*)&As[cur][(wm + x * 16 + l16) * 32 + quad * 8];
#pragma unroll
    for (int j = 0; j < 4; ++j) bfv[j] = *(const bf16x8*)(const void*)&Bs[cur][(wn + j * 16 + l16) * 32 + quad * 8];
    asm volatile("s_waitcnt lgkmcnt(0)\n\ts_barrier" ::: "memory");
    if (i + 2 < NK) STAGE_BT(cur, (i + 2) * 32);
#pragma unroll
    for (int x = 0; x < 4; ++x)
#pragma unroll
      for (int j = 0; j < 4; ++j)
        acc[x][j] = __builtin_amdgcn_mfma_f32_16x16x32_bf16(af[x], bfv[j], acc[x][j], 0, 0, 0);
    cur ^= 1;
  }
  asm volatile("s_waitcnt vmcnt(0)\n\ts_barrier" ::: "memory");
  {
    bf16x8 af[4], bfv[4];
#pragma unroll
    for (int x = 0; x < 4; ++x) af[x] = *(const bf16x8*)(const void*)&As[cur][(wm + x * 16 + l16) * 32 + quad * 8];
#pragma unroll
    for (int j = 0; j < 4; ++j) bfv[j] = *(const bf16x8*)(const void*)&Bs[cur][(wn + j * 16 + l16) * 32 + quad * 8];
#pragma unroll
    for (int x = 0; x < 4; ++x)
#pragma unroll
      for (int j = 0; j < 4; ++j)
        acc[x][j] = __builtin_amdgcn_mfma_f32_16x16x32_bf16(af[x], bfv[j], acc[x][j], 0, 0, 0);
  }
#undef STAGE_BT

#pragma unroll
  for (int i = 0; i < 4; ++i) {
    const int gm = m0 + wm + i * 16 + quad * 4;
#pragma unroll
    for (int j = 0; j < 4; ++j) {
      const int gn = n0 + wn + j * 16 + l16;
      const float bv = b2f(bias[gn]);
#pragma unroll
      for (int r = 0; r < 4; ++r)
        gemm_epi<EPI>(acc[i][j][r] + bv, gm + r, gn, N, out, gate, res0, res1, oflags);
    }
  }
}

// 128x64-tile variant for N=1024-class GEMMs (2x grid vs 128x128).
template <int EPI>
__global__ __launch_bounds__(256) void gemm_bt64(
    const us* __restrict__ A, const us* __restrict__ BT,
    const us* __restrict__ bias, void* __restrict__ out,
    int M, int N, int K,
    const us* __restrict__ gate,
    const void* __restrict__ res0, const void* __restrict__ res1,
    const int* __restrict__ oflags) {
  __shared__ __attribute__((aligned(16))) us As[2][128 * 32];
  __shared__ __attribute__((aligned(16))) us Bs[2][64 * 32];
  const int m0 = blockIdx.x * 128, n0 = blockIdx.y * 64;
  const int t = threadIdx.x;
  const int wave = t >> 6, lane = t & 63;
  const int wm = (wave >> 1) * 64, wn = (wave & 1) * 32;
  const int l16 = lane & 15, quad = lane >> 4;
  f32x4 acc[4][2] = {};

  const int lr = lane >> 2, lc = (lane & 3) * 8;
  const us* gA = A + (size_t)(m0 + wave * 32 + lr) * K + lc;
  const us* gB = BT + (size_t)(n0 + wave * 16 + lr) * K + lc;
  const int woA = wave * 1024, woB = wave * 512;

#define STAGE_BT64(buf, k)                                  \
  { us* pA = &As[buf][woA];                                 \
    gl2lds16(gA + (k), pA);                                 \
    gl2lds16(gA + (size_t)16 * K + (k), pA + 512);          \
    gl2lds16(gB + (k), &Bs[buf][woB]); }

  STAGE_BT64(0, 0);
  STAGE_BT64(1, 32);
  const int NK = K >> 5;
  int cur = 0;
  for (int i = 0; i < NK - 1; ++i) {
    asm volatile("s_waitcnt vmcnt(3)\n\ts_barrier" ::: "memory");
    bf16x8 af[4], bfv[2];
#pragma unroll
    for (int x = 0; x < 4; ++x) af[x] = *(const bf16x8*)(const void*)&As[cur][(wm + x * 16 + l16) * 32 + quad * 8];
#pragma unroll
    for (int j = 0; j < 2; ++j) bfv[j] = *(const bf16x8*)(const void*)&Bs[cur][(wn + j * 16 + l16) * 32 + quad * 8];
    asm volatile("s_waitcnt lgkmcnt(0)\n\ts_barrier" ::: "memory");
    if (i + 2 < NK) STAGE_BT64(cur, (i + 2) * 32);
#pragma unroll
    for (int x = 0; x < 4; ++x)
#pragma unroll
      for (int j = 0; j < 2; ++j)
        acc[x][j] = __builtin_amdgcn_mfma_f32_16x16x32_bf16(af[x], bfv[j], acc[x][j], 0, 0, 0);
    cur ^= 1;
  }
  asm volatile("s_waitcnt vmcnt(0)\n\ts_barrier" ::: "memory");
  {
    bf16x8 af[4], bfv[2];
#pragma unroll
    for (int x = 0; x < 4; ++x) af[x] = *(const bf16x8*)(const void*)&As[cur][(wm + x * 16 + l16) * 32 + quad * 8];
#pragma unroll
    for (int j = 0; j < 2; ++j) bfv[j] = *(const bf16x8*)(const void*)&Bs[cur][(wn + j * 16 + l16) * 32 + quad * 8];
#pragma unroll
    for (int x = 0; x < 4; ++x)
#pragma unroll
      for (int j = 0; j < 2; ++j)
        acc[x][j] = __builtin_amdgcn_mfma_f32_16x16x32_bf16(af[x], bfv[j], acc[x][j], 0, 0, 0);
  }
#undef STAGE_BT64

#pragma unroll
  for (int i = 0; i < 4; ++i) {
    const int gm = m0 + wm + i * 16 + quad * 4;
#pragma unroll
    for (int j = 0; j < 2; ++j) {
      const int gn = n0 + wn + j * 16 + l16;
      const float bv = b2f(bias[gn]);
#pragma unroll
      for (int r = 0; r < 4; ++r)
        gemm_epi<EPI>(acc[i][j][r] + bv, gm + r, gn, N, out, gate, res0, res1, oflags);
    }
  }
}

// ---------------------------------------------------------------------------
// MFMA flash attention (r6-proven): unified single-64-key rounds, serial
// stage between barriers, complementary tile pairing, setprio around MFMA.
// LDS: K + V + P = 27.6 KB.
// ---------------------------------------------------------------------------
struct AttnState { float m[4], l[4]; f32x4 o[4]; };

DEVI void st_init(AttnState& s) {
#pragma unroll
  for (int r = 0; r < 4; ++r) { s.m[r] = NEGINF; s.l[r] = 0.f; s.o[r] = f32x4{}; }
}

// Stage a 64-row x 64-col bf16 tile into LDS [64][72] (256 threads, 2 iters).
DEVI void stage64(us* __restrict__ dst, const us* __restrict__ src,
                  int strideUs, int t) {
#pragma unroll
  for (int it = 0; it < 2; ++it) {
    const int id = it * 256 + t;
    const int row = id >> 3, c8 = (id & 7) * 8;
    *(uint4*)&dst[row * 72 + c8] = *(const uint4*)(src + (size_t)row * strideUs + c8);
  }
}

template <bool MASKED>
DEVI void attn_round(const us* __restrict__ Kb, const us* __restrict__ Vb,
                     us* __restrict__ Pb, const ull* mrow,
                     bf16x8 aq0, bf16x8 aq1, AttnState& st,
                     int wv, int l16, int quad) {
  f32x4 s[4];
  __builtin_amdgcn_s_setprio(1);
#pragma unroll
  for (int j = 0; j < 4; ++j) {
    const int row = j * 16 + l16;
    bf16x8 bk0 = *(const bf16x8*)(const void*)&Kb[row * 72 + quad * 8];
    bf16x8 bk1 = *(const bf16x8*)(const void*)&Kb[row * 72 + 32 + quad * 8];
    f32x4 z = {};
    z = __builtin_amdgcn_mfma_f32_16x16x32_bf16(aq0, bk0, z, 0, 0, 0);
    z = __builtin_amdgcn_mfma_f32_16x16x32_bf16(aq1, bk1, z, 0, 0, 0);
    s[j] = z;
  }
  __builtin_amdgcn_s_setprio(0);
  const float CE = 0.18033688011112042f;  // 0.125 * log2(e)
#pragma unroll
  for (int r = 0; r < 4; ++r) {
    float mx = fmaxf(fmaxf(s[0][r], s[1][r]), fmaxf(s[2][r], s[3][r]));
#pragma unroll
    for (int o2 = 8; o2; o2 >>= 1) mx = fmaxf(mx, __shfl_xor(mx, o2));
    const float mn = fmaxf(st.m[r], mx);
    const float alpha = exp2f((st.m[r] - mn) * CE);  // -inf start -> 0
    const float mnC = mn * CE;
    float rs = 0.f;
#pragma unroll
    for (int j = 0; j < 4; ++j) {
      float p = exp2f(__builtin_fmaf(s[j][r], CE, -mnC));
      if constexpr (MASKED) p = ((mrow[r] >> (j * 16 + l16)) & 1ull) ? p : 0.f;
      rs += p;
      ((__bf16*)Pb)[(wv * 16 + quad * 4 + r) * 72 + j * 16 + l16] = (__bf16)p;
    }
#pragma unroll
    for (int o2 = 8; o2; o2 >>= 1) rs += __shfl_xor(rs, o2);
    st.m[r] = mn;
    st.l[r] = st.l[r] * alpha + rs;
#pragma unroll
    for (int jd = 0; jd < 4; ++jd) st.o[jd][r] *= alpha;
  }
  bf16x8 ap0 = *(const bf16x8*)(const void*)&Pb[(wv * 16 + l16) * 72 + quad * 8];
  bf16x8 ap1 = *(const bf16x8*)(const void*)&Pb[(wv * 16 + l16) * 72 + 32 + quad * 8];
  __builtin_amdgcn_s_setprio(1);
#pragma unroll
  for (int jd = 0; jd < 4; ++jd) {
    bf16x8 v0 = *(const bf16x8*)(const void*)&Vb[(jd * 16 + l16) * 72 + quad * 8];
    bf16x8 v1 = *(const bf16x8*)(const void*)&Vb[(jd * 16 + l16) * 72 + 32 + quad * 8];
    st.o[jd] = __builtin_amdgcn_mfma_f32_16x16x32_bf16(ap0, v0, st.o[jd], 0, 0, 0);
    st.o[jd] = __builtin_amdgcn_mfma_f32_16x16x32_bf16(ap1, v1, st.o[jd], 0, 0, 0);
  }
  __builtin_amdgcn_s_setprio(0);
}

DEVI void attn_write(us* __restrict__ y, const AttnState& st, int rowAbs,
                     int h, int l16, int quad) {
#pragma unroll
  for (int r = 0; r < 4; ++r) {
    const float inv = (st.l[r] > 0.f) ? 1.f / st.l[r] : 0.f;
#pragma unroll
    for (int jd = 0; jd < 4; ++jd)
      y[(size_t)(rowAbs + quad * 4 + r) * 1024 + h * 64 + jd * 16 + l16] =
          f2b(st.o[jd][r] * inv);
  }
}

// Cross: 256 keys = 4 rounds; no masks.
__global__ __launch_bounds__(256) void cross_attn_mfma(
    const us* __restrict__ q, const us* __restrict__ kv,
    const us* __restrict__ vT, us* __restrict__ y) {
  __shared__ __attribute__((aligned(16))) us Kb[64 * 72];
  __shared__ __attribute__((aligned(16))) us Vb[64 * 72];
  __shared__ __attribute__((aligned(16))) us Pb[64 * 72];
  const int bid = blockIdx.x;
  const int xcd = bid & 7, tmp = bid >> 3;
  const int tt = tmp & 15, gq = tmp >> 4;
  const int g = gq * 8 + xcd;          // (st,b,h) group
  const int strm = g >> 5, b = (g >> 4) & 1, h = g & 15;
  const int t = threadIdx.x, wv = t >> 6, lane = t & 63;
  const int l16 = lane & 15, quad = lane >> 4;
  const int rowbase = strm * 2048 + b * 1024 + tt * 64 + wv * 16;
  const us* qp = q + (size_t)(rowbase + l16) * 1024 + h * 64 + quad * 8;
  bf16x8 aq0 = *(const bf16x8*)(qp);
  bf16x8 aq1 = *(const bf16x8*)(qp + 32);
  const us* kb = kv + (size_t)b * (256 * 2048) + h * 64;
  const us* vb = vT + (size_t)(b * 16 + h) * (64 * 256);
  AttnState st; st_init(st);
  for (int rnd = 0; rnd < 4; ++rnd) {
    const int s0 = rnd * 64;
    __syncthreads();
    stage64(Kb, kb + (size_t)s0 * 2048, 2048, t);
    stage64(Vb, vb + s0, 256, t);
    __syncthreads();
    attn_round<false>(Kb, Vb, Pb, nullptr, aq0, aq1, st, wv, l16, quad);
  }
  attn_write(y, st, rowbase, h, l16, quad);
}

// Star: causal+dep; only the diagonal chunk needs the causal bits.
DEVI void star_body(us* Kb, us* Vb, us* Pb, const us* qkv, const us* vT,
                    const ull* depb, us* y, int b, int h, int tt, int t) {
  const int wv = t >> 6, lane = t & 63;
  const int l16 = lane & 15, quad = lane >> 4;
  const int t0 = tt * 64;
  const int rowbase = b * 1024 + t0 + wv * 16;
  const us* qp = qkv + (size_t)(rowbase + l16) * 3072 + h * 64 + quad * 8;
  bf16x8 aq0 = *(const bf16x8*)(qp);
  bf16x8 aq1 = *(const bf16x8*)(qp + 32);
  const us* kb = qkv + (size_t)(b * 1024) * 3072 + 1024 + h * 64;
  const us* vb = vT + (size_t)(b * 16 + h) * 65536;
  AttnState st; st_init(st);
  ull mrow[4];
  for (int ck = 0; ck <= tt; ++ck) {
    const int s0 = ck * 64;
    __syncthreads();
    stage64(Kb, kb + (size_t)s0 * 3072, 3072, t);
    stage64(Vb, vb + s0, 1024, t);
    __syncthreads();
#pragma unroll
    for (int r = 0; r < 4; ++r) {
      ull d = depb[(size_t)(rowbase + quad * 4 + r) * 16 + ck];
      if (ck == tt) {
        const int idx = wv * 16 + quad * 4 + r;  // trow - s0 (t0 == s0 here)
        d &= (2ull << idx) - 1ull;               // bits 0..idx (idx=63 -> ~0)
      }
      mrow[r] = d;
    }
    attn_round<true>(Kb, Vb, Pb, mrow, aq0, aq1, st, wv, l16, quad);
  }
  attn_write(y, st, rowbase, h, l16, quad);
}

// Hat: star-part and hat-part processed as independent rounds, each gated by
// its own block flag bit.
DEVI void hat_body(us* Kb, us* Vb, us* Pb, const us* qkv,
                   const us* vsT, const us* vhT,
                   const ull* starb, const ull* hatb, const ull* depb,
                   const int* bflags, us* y, int b, int h, int tt, int t) {
  const int wv = t >> 6, lane = t & 63;
  const int l16 = lane & 15, quad = lane >> 4;
  const int t0 = tt * 64;
  const int rowbase = b * 1024 + t0 + wv * 16;
  const us* qp = qkv + (size_t)(2048 + rowbase + l16) * 3072 + h * 64 + quad * 8;
  bf16x8 aq0 = *(const bf16x8*)(qp);
  bf16x8 aq1 = *(const bf16x8*)(qp + 32);
  const us* ksb = qkv + (size_t)(b * 1024) * 3072 + 1024 + h * 64;
  const us* khb = qkv + (size_t)(2048 + b * 1024) * 3072 + 1024 + h * 64;
  const us* vsb = vsT + (size_t)(b * 16 + h) * 65536;
  const us* vhb = vhT + (size_t)(b * 16 + h) * 65536;
  AttnState st; st_init(st);
  ull mrow[4];
  for (int ck = 0; ck < 16; ++ck) {
    const int f = bflags[(b * 16 + tt) * 16 + ck];
    const int s0 = ck * 64;
    if (f & 1) {  // star-visible keys of this chunk
      __syncthreads();
      stage64(Kb, ksb + (size_t)s0 * 3072, 3072, t);
      stage64(Vb, vsb + s0, 1024, t);
      __syncthreads();
#pragma unroll
      for (int r = 0; r < 4; ++r) {
        const size_t mi = (size_t)(rowbase + quad * 4 + r) * 16 + ck;
        mrow[r] = starb[mi] & depb[mi];
      }
      attn_round<true>(Kb, Vb, Pb, mrow, aq0, aq1, st, wv, l16, quad);
    }
    if (f & 2) {  // hat-visible keys of this chunk
      __syncthreads();
      stage64(Kb, khb + (size_t)s0 * 3072, 3072, t);
      stage64(Vb, vhb + s0, 1024, t);
      __syncthreads();
#pragma unroll
      for (int r = 0; r < 4; ++r) {
        const size_t mi = (size_t)(rowbase + quad * 4 + r) * 16 + ck;
        mrow[r] = hatb[mi] & depb[mi];
      }
      attn_round<true>(Kb, Vb, Pb, mrow, aq0, aq1, st, wv, l16, quad);
    }
  }
  attn_write(y, st, 2048 + rowbase, h, l16, quad);
}

// XCD-swizzled merged self-attention with complementary-pair load balance.
__global__ __launch_bounds__(256) void self_attn_mfma(
    const us* __restrict__ qkv,
    const us* __restrict__ vstT, const us* __restrict__ vhtT,
    const ull* __restrict__ sbits, const ull* __restrict__ hbits,
    const ull* __restrict__ dbits, const int* __restrict__ bflags,
    us* __restrict__ y) {
  __shared__ __attribute__((aligned(16))) us Kb[64 * 72];
  __shared__ __attribute__((aligned(16))) us Vb[64 * 72];
  __shared__ __attribute__((aligned(16))) us Pb[64 * 72];
  const int bid = blockIdx.x;
  const int xcd = bid & 7, tmp = bid >> 3;
  const int pr = tmp & 7, gq = tmp >> 3;
  const int g = gq * 8 + xcd;
  const int ttA = pr, ttB = 15 - pr;
  const int t = threadIdx.x;
  if (g < 32) {
    star_body(Kb, Vb, Pb, qkv, vstT, dbits, y, g >> 4, g & 15, ttA, t);
    star_body(Kb, Vb, Pb, qkv, vstT, dbits, y, g >> 4, g & 15, ttB, t);
  } else {
    const int g2 = g - 32;
    hat_body(Kb, Vb, Pb, qkv, vstT, vhtT, sbits, hbits, dbits, bflags,
             y, g2 >> 4, g2 & 15, ttA, t);
    hat_body(Kb, Vb, Pb, qkv, vstT, vhtT, sbits, hbits, dbits, bflags,
             y, g2 >> 4, g2 & 15, ttB, t);
  }
}

// ---------------------------------------------------------------------------
extern "C" void kernel_launch(void* const* d_in, const int* in_sizes, int n_in,
                              void* d_out, int out_size, void* d_ws, size_t ws_size,
                              hipStream_t stream) {
  const void* xs = d_in[0];
  const void* xh = d_in[1];
  const void* cc = d_in[2];
  const void* mstar = d_in[3];
  const void* mhat = d_in[4];
  const void* mdep = d_in[5];
  const void* ng = d_in[6];
  const void* nb = d_in[7];
  const void* Wq = d_in[8];
  const void* bq = d_in[9];
  const void* Wkv = d_in[10];
  const void* bkv = d_in[11];
  const void* Wco = d_in[12];
  const void* bco = d_in[13];
  const void* Wada = d_in[14];
  const void* bada = d_in[15];
  const void* Wqkv = d_in[16];
  const void* bqkv = d_in[17];
  const void* Wo = d_in[18];
  const void* bo = d_in[19];
  const void* W1 = d_in[20];
  const void* b1 = d_in[21];
  const void* W2 = d_in[22];
  const void* b2 = d_in[23];
  (void)in_sizes; (void)n_in; (void)out_size; (void)ws_size;

  char* ws = (char*)d_ws;
  size_t off = 0;
  auto alloc = [&](size_t bytes) -> char* {
    char* p = ws + off;
    off += (bytes + 255) & ~(size_t)255;
    return p;
  };
  int* flags = (int*)alloc(256);
  int* bflags = (int*)alloc(512 * 4);
  us* smallb = (us*)alloc(21504 * 2);
  us* ngb = smallb, *nbb = smallb + 1024, *bqb = smallb + 2048,
      *bkvb = smallb + 3072, *bcob = smallb + 5120, *badab = smallb + 6144,
      *bqkvb = smallb + 12288, *bob = smallb + 15360, *b1b = smallb + 16384,
      *b2b = smallb + 20480;
  us* WqT = (us*)alloc(1048576ull * 2);
  us* WkvT = (us*)alloc(2097152ull * 2);
  us* WcoT = (us*)alloc(1048576ull * 2);
  us* WadaT = (us*)alloc(6291456ull * 2);
  us* WqkvT = (us*)alloc(3145728ull * 2);
  us* WoT = (us*)alloc(1048576ull * 2);
  us* W1T = (us*)alloc(4194304ull * 2);
  us* W2T = (us*)alloc(4194304ull * 2);
  us* xn = (us*)alloc(4194304ull * 2);
  us* qb = (us*)alloc(4194304ull * 2);
  us* kvb = (us*)alloc(1048576ull * 2);
  us* gada = (us*)alloc(25165824ull * 2);
  us* msb = (us*)alloc(4194304ull * 2);
  us* qkvb = (us*)alloc(12582912ull * 2);
  float* x1 = (float*)alloc(4194304ull * 4);
  us* hid = (us*)alloc(16777216ull * 2);
  ull* mb = (ull*)alloc(3ull * 32768 * 8);
  us* kvT = (us*)alloc(524288ull * 2);
  us* vstT = (us*)alloc(2097152ull * 2);
  us* vhtT = (us*)alloc(2097152ull * 2);

  ull* sbits = mb;
  ull* hbits = mb + 32768;
  ull* dbits = mb + 65536;
  us* ccb = hid;              // dead before hid written
  us* lnx = hid + 1048576;    // dead before hid written
  us* yca = xn;
  us* silub = qb;
  us* yat = msb;

  dim3 blk(256);
  detect_flags<<<1, blk, 0, stream>>>((const unsigned int*)xs, (const unsigned int*)mdep, flags);

  cvt_bf16<<<512, blk, 0, stream>>>(cc, ccb, 524288, flags);
  P10 ps10; ps10.p[0] = ng; ps10.p[1] = nb; ps10.p[2] = bq; ps10.p[3] = bkv;
  ps10.p[4] = bco; ps10.p[5] = bada; ps10.p[6] = bqkv; ps10.p[7] = bo;
  ps10.p[8] = b1; ps10.p[9] = b2;
  cvt_small<<<84, blk, 0, stream>>>(ps10, smallb, flags);

  transpose_cvt64<<<dim3(16, 16), blk, 0, stream>>>(Wq, WqT, 1024, 1024, flags);
  transpose_cvt64<<<dim3(16, 32), blk, 0, stream>>>(Wkv, WkvT, 1024, 2048, flags);
  transpose_cvt64<<<dim3(16, 16), blk, 0, stream>>>(Wco, WcoT, 1024, 1024, flags);
  transpose_cvt64<<<dim3(16, 96), blk, 0, stream>>>(Wada, WadaT, 1024, 6144, flags);
  transpose_cvt64<<<dim3(16, 48), blk, 0, stream>>>(Wqkv, WqkvT, 1024, 3072, flags);
  transpose_cvt64<<<dim3(16, 16), blk, 0, stream>>>(Wo, WoT, 1024, 1024, flags);
  transpose_cvt64<<<dim3(16, 64), blk, 0, stream>>>(W1, W1T, 1024, 4096, flags);
  transpose_cvt64<<<dim3(64, 16), blk, 0, stream>>>(W2, W2T, 4096, 1024, flags);

  P3 ps3; ps3.p[0] = mstar; ps3.p[1] = mhat; ps3.p[2] = mdep;
  pack_mask3<<<dim3(512, 3), blk, 0, stream>>>(ps3, mb, flags);
  hat_blockflags<<<32, blk, 0, stream>>>(sbits, hbits, bflags);

  ln_affine<<<4096, blk, 0, stream>>>(xs, xh, ngb, nbb, lnx, xn, flags);
  gemm_bt64<EPI_BF16><<<dim3(32, 16), blk, 0, stream>>>(xn, WqT, bqb, qb, 4096, 1024, 1024, nullptr, nullptr, nullptr, nullptr);
  gemm_bt64<EPI_BF16><<<dim3(4, 32), blk, 0, stream>>>(ccb, WkvT, bkvb, kvb, 512, 2048, 1024, nullptr, nullptr, nullptr, nullptr);
  vtrans<<<dim3(4, 32), blk, 0, stream>>>(kvb, kvT, 256, 2048, 1024, 0);
  cross_attn_mfma<<<1024, blk, 0, stream>>>(qb, kvb, kvT, yca);
  gemm_bt64<EPI_SILU><<<dim3(32, 16), blk, 0, stream>>>(yca, WcoT, bcob, silub, 4096, 1024, 1024, nullptr, nullptr, nullptr, nullptr);
  gemm_bt<EPI_BF16><<<dim3(32, 48), blk, 0, stream>>>(silub, WadaT, badab, gada, 4096, 6144, 1024, nullptr, nullptr, nullptr, nullptr);
  mod_ms<<<4096, blk, 0, stream>>>(lnx, gada, msb);
  gemm_bt<EPI_BF16><<<dim3(32, 24), blk, 0, stream>>>(msb, WqkvT, bqkvb, qkvb, 4096, 3072, 1024, nullptr, nullptr, nullptr, nullptr);
  vtrans_qkv<<<dim3(16, 32, 2), blk, 0, stream>>>(qkvb, vstT, vhtT);
  self_attn_mfma<<<512, blk, 0, stream>>>(qkvb, vstT, vhtT, sbits, hbits, dbits, bflags, yat);
  gemm_bt64<EPI_GATE_XRES><<<dim3(32, 16), blk, 0, stream>>>(yat, WoT, bob, x1, 4096, 1024, 1024, gada + 2048, xs, xh, flags);
  ln_mod<<<4096, blk, 0, stream>>>(x1, gada, msb);
  gemm_bt<EPI_GELU><<<dim3(32, 32), blk, 0, stream>>>(msb, W1T, b1b, hid, 4096, 4096, 1024, nullptr, nullptr, nullptr, nullptr);
  gemm_bt64<EPI_GATE_OUT><<<dim3(32, 16), blk, 0, stream>>>(hid, W2T, b2b, d_out, 4096, 1024, 4096, gada + 5120, x1, nullptr, flags);
}

// Round 12
// 617.827 us; speedup vs baseline: 1.1785x; 1.0075x over previous
//
#include <hip/hip_runtime.h>
#include <hip/hip_bf16.h>
#include <stdint.h>

#define DEVI __device__ __forceinline__

typedef __bf16 bf16x8 __attribute__((ext_vector_type(8)));
typedef float f32x4 __attribute__((ext_vector_type(4)));
typedef unsigned short us;
typedef unsigned long long ull;

DEVI float b2f(us u) { union { unsigned int i; float f; } v; v.i = ((unsigned int)u) << 16; return v.f; }
DEVI us f2b(float f) {
  union { unsigned int i; float f; } v; v.f = f;
  unsigned int r = (v.i + 0x7fffu + ((v.i >> 16) & 1u)) >> 16;
  return (us)r;
}

#define NEGINF (-__builtin_inff())

DEVI void gl2lds16(const us* g, us* l) {
  __builtin_amdgcn_global_load_lds(
      (const __attribute__((address_space(1))) unsigned int*)g,
      (__attribute__((address_space(3))) unsigned int*)l, 16, 0, 0);
}

// ---------------------------------------------------------------------------
// Runtime dtype detection. flags[0]: f32 inputs; flags[1]: byte-packed masks.
// ---------------------------------------------------------------------------
__global__ __launch_bounds__(256) void detect_flags(
    const unsigned int* __restrict__ xw, const unsigned int* __restrict__ mw,
    int* __restrict__ flags) {
  const int t = threadIdx.x;
  int cnt = 0, big = 0;
  for (int i = t; i < 4096; i += 256) {
    unsigned int w = xw[i];
    us lo = (us)(w & 0xffffu);
    float a = fabsf(b2f(lo));
    cnt += ((lo == 0) || (a >= 1e-8f && a <= 256.f)) ? 1 : 0;
    big |= (mw[i] > 1u) ? 1 : 0;
  }
  for (int o = 32; o; o >>= 1) { cnt += __shfl_down(cnt, o); big |= __shfl_down(big, o); }
  __shared__ int sc[4], sb[4];
  if ((t & 63) == 0) { sc[t >> 6] = cnt; sb[t >> 6] = big; }
  __syncthreads();
  if (t == 0) {
    flags[0] = (sc[0] + sc[1] + sc[2] + sc[3] < 2048) ? 1 : 0;
    flags[1] = (sb[0] | sb[1] | sb[2] | sb[3]);
  }
}

__global__ __launch_bounds__(256) void cvt_bf16(
    const void* __restrict__ src, us* __restrict__ dst, int n,
    const int* __restrict__ flags) {
  const int f32mode = flags[0];
  int idx = (blockIdx.x * 256 + threadIdx.x) * 4;
  if (idx >= n) return;
  if (f32mode) {
    const float* s = (const float*)src;
    float4 v = *(const float4*)(s + idx);
    dst[idx] = f2b(v.x); dst[idx + 1] = f2b(v.y);
    dst[idx + 2] = f2b(v.z); dst[idx + 3] = f2b(v.w);
  } else {
    *(uint2*)(dst + idx) = *(const uint2*)((const us*)src + idx);
  }
}

struct P10 { const void* p[10]; };
__global__ __launch_bounds__(256) void cvt_small(P10 ps, us* __restrict__ dst,
                                                 const int* __restrict__ flags) {
  const int offs[11] = {0, 1024, 2048, 3072, 5120, 6144, 12288, 15360, 16384, 20480, 21504};
  int idx = blockIdx.x * 256 + threadIdx.x;
  if (idx >= 21504) return;
  int seg = 0;
#pragma unroll
  for (int i = 1; i < 10; ++i) seg += (idx >= offs[i]) ? 1 : 0;
  int local = idx - offs[seg];
  float v = flags[0] ? ((const float*)ps.p[seg])[local]
                     : b2f(((const us*)ps.p[seg])[local]);
  dst[idx] = f2b(v);
}

// Vectorized 64x64 convert+transpose: W (K,N) f32/bf16 -> WT (N,K) bf16.
__global__ __launch_bounds__(256) void transpose_cvt64(
    const void* __restrict__ W, us* __restrict__ WT, int K, int N,
    const int* __restrict__ flags) {
  __shared__ __attribute__((aligned(16))) us tile[64 * 72];
  const int f32m = flags[0];
  const int k0 = blockIdx.x * 64, n0 = blockIdx.y * 64;
  const int t = threadIdx.x;
  const int row = t >> 2, colb = (t & 3) * 16;
  const int sw = ((row >> 4) & 3) << 4;
  us tmp[16];
  if (f32m) {
    const float* src = (const float*)W + (size_t)(k0 + row) * N + n0 + colb;
#pragma unroll
    for (int i = 0; i < 16; i += 4) {
      float4 v = *(const float4*)(src + i);
      tmp[i] = f2b(v.x); tmp[i + 1] = f2b(v.y); tmp[i + 2] = f2b(v.z); tmp[i + 3] = f2b(v.w);
    }
  } else {
    const us* src = (const us*)W + (size_t)(k0 + row) * N + n0 + colb;
    *(uint4*)tmp = *(const uint4*)src;
    *(uint4*)(tmp + 8) = *(const uint4*)(src + 8);
  }
  *(uint4*)&tile[row * 72 + (colb ^ sw)] = *(uint4*)tmp;
  *(uint4*)&tile[row * 72 + (colb ^ sw) + 8] = *(uint4*)(tmp + 8);
  __syncthreads();
  const int orow = t >> 2, ocolb = (t & 3) * 16;
  const int pc = (orow & 15) | ((orow & 48) ^ (ocolb & 48));
  us out[16];
#pragma unroll
  for (int i = 0; i < 16; ++i) out[i] = tile[(ocolb + i) * 72 + pc];
  us* dst = WT + (size_t)(n0 + orow) * K + k0 + ocolb;
  *(uint4*)dst = *(uint4*)out;
  *(uint4*)(dst + 8) = *(uint4*)(out + 8);
}

struct P3 { const void* p[3]; };
__global__ __launch_bounds__(256) void pack_mask3(P3 ms, ull* __restrict__ bits,
                                                  const int* __restrict__ flags) {
  const int bytemode = flags[1];
  const void* m = ms.p[blockIdx.y];
  ull* out = bits + (size_t)blockIdx.y * 32768;
  int wv = blockIdx.x * 4 + (threadIdx.x >> 6);
  int lane = threadIdx.x & 63;
  for (int w = 0; w < 16; ++w) {
    int v;
    if (bytemode) v = ((const unsigned char*)m)[(size_t)wv * 1024 + w * 64 + lane];
    else          v = ((const int*)m)[(size_t)wv * 1024 + w * 64 + lane];
    ull b = __ballot(v != 0);
    if (lane == 0) out[(size_t)wv * 16 + w] = b;
  }
}

__global__ __launch_bounds__(256) void hat_blockflags(
    const ull* __restrict__ starb, const ull* __restrict__ hatb, int* __restrict__ bf) {
  const int bt = blockIdx.x;
  const int b = bt >> 4, tt = bt & 15;
  const int t = threadIdx.x, wv = t >> 6, lane = t & 63;
  const int t0 = tt * 64;
  for (int k = 0; k < 4; ++k) {
    int ck = wv * 4 + k;
    ull sw = starb[(size_t)(b * 1024 + t0 + lane) * 16 + ck];
    ull hw = hatb[(size_t)(b * 1024 + t0 + lane) * 16 + ck];
    int f = (__ballot(sw != 0ull) ? 1 : 0) | (__ballot(hw != 0ull) ? 2 : 0);
    if (lane == 0) bf[bt * 16 + ck] = f;
  }
}

// V transpose to [bh][64(d)][T]
__global__ __launch_bounds__(256) void vtrans(
    const us* __restrict__ src, us* __restrict__ dst,
    int T, int stride, int colBase, int rowOff) {
  __shared__ __attribute__((aligned(16))) us tile[64][65];
  const int bh = blockIdx.y, b = bh >> 4, h = bh & 15;
  const int t0 = blockIdx.x * 64;
  const int t = threadIdx.x;
#pragma unroll
  for (int it = 0; it < 2; ++it) {
    int idx = it * 256 + t; int r = idx >> 3, c8 = (idx & 7) * 8;
    uint4 d4 = *(const uint4*)(src + (size_t)(rowOff + b * T + t0 + r) * stride + colBase + h * 64 + c8);
    const us* e = (const us*)&d4;
#pragma unroll
    for (int i = 0; i < 8; ++i) tile[r][c8 + i] = e[i];
  }
  __syncthreads();
#pragma unroll
  for (int it = 0; it < 2; ++it) {
    int idx = it * 256 + t; int d = idx >> 3, c8 = (idx & 7) * 8;
    us tmp[8];
#pragma unroll
    for (int i = 0; i < 8; ++i) tmp[i] = tile[c8 + i][d];
    *(uint4*)(dst + ((size_t)(bh * 64 + d)) * T + t0 + c8) = *(const uint4*)tmp;
  }
}

// Both self-attn V transposes (star z=0, hat z=1) in one launch.
__global__ __launch_bounds__(256) void vtrans_qkv(
    const us* __restrict__ src, us* __restrict__ dst0, us* __restrict__ dst1) {
  __shared__ __attribute__((aligned(16))) us tile[64][65];
  const int z = blockIdx.z;
  us* dst = z ? dst1 : dst0;
  const int rowOff = z ? 2048 : 0;
  const int bh = blockIdx.y, b = bh >> 4, h = bh & 15;
  const int t0 = blockIdx.x * 64;
  const int t = threadIdx.x;
#pragma unroll
  for (int it = 0; it < 2; ++it) {
    int idx = it * 256 + t; int r = idx >> 3, c8 = (idx & 7) * 8;
    uint4 d4 = *(const uint4*)(src + (size_t)(rowOff + b * 1024 + t0 + r) * 3072 + 2048 + h * 64 + c8);
    const us* e = (const us*)&d4;
#pragma unroll
    for (int i = 0; i < 8; ++i) tile[r][c8 + i] = e[i];
  }
  __syncthreads();
#pragma unroll
  for (int it = 0; it < 2; ++it) {
    int idx = it * 256 + t; int d = idx >> 3, c8 = (idx & 7) * 8;
    us tmp[8];
#pragma unroll
    for (int i = 0; i < 8; ++i) tmp[i] = tile[c8 + i][d];
    *(uint4*)(dst + ((size_t)(bh * 64 + d)) * 1024 + t0 + c8) = *(const uint4*)tmp;
  }
}

// ---------------------------------------------------------------------------
// LayerNorm + modulation
// ---------------------------------------------------------------------------
__global__ __launch_bounds__(256) void ln_affine(
    const void* __restrict__ xs, const void* __restrict__ xh,
    const us* __restrict__ gw, const us* __restrict__ bw,
    us* __restrict__ lnx, us* __restrict__ xn, const int* __restrict__ flags) {
  const int f32m = flags[0];
  const int row = blockIdx.x;
  const void* xp = (row < 2048) ? xs : xh;
  const size_t base = (size_t)(row & 2047) * 1024;
  const int t = threadIdx.x;
  float v[4]; float s = 0.f, ss = 0.f;
#pragma unroll
  for (int i = 0; i < 4; ++i) {
    size_t idx = base + i * 256 + t;
    float x = f32m ? ((const float*)xp)[idx] : b2f(((const us*)xp)[idx]);
    v[i] = x; s += x; ss += x * x;
  }
  for (int o = 32; o; o >>= 1) { s += __shfl_down(s, o); ss += __shfl_down(ss, o); }
  __shared__ float red[2][4];
  const int wv = t >> 6, lane = t & 63;
  if (lane == 0) { red[0][wv] = s; red[1][wv] = ss; }
  __syncthreads();
  s = red[0][0] + red[0][1] + red[0][2] + red[0][3];
  ss = red[1][0] + red[1][1] + red[1][2] + red[1][3];
  const float mean = s * (1.f / 1024.f);
  const float var = fmaxf(ss * (1.f / 1024.f) - mean * mean, 0.f);
  const float rstd = rsqrtf(var + 1e-6f);
  const size_t ro = (size_t)row * 1024;
#pragma unroll
  for (int i = 0; i < 4; ++i) {
    int c = i * 256 + t;
    float n = (v[i] - mean) * rstd;
    lnx[ro + c] = f2b(n);
    xn[ro + c] = f2b(n * b2f(gw[c]) + b2f(bw[c]));
  }
}

__global__ __launch_bounds__(256) void mod_ms(
    const us* __restrict__ lnx, const us* __restrict__ gada, us* __restrict__ ms) {
  const size_t idx = ((size_t)blockIdx.x * 256 + threadIdx.x) * 4;
  const int row = (int)(idx >> 10), c = (int)(idx & 1023);
  const size_t gb = (size_t)row * 6144;
#pragma unroll
  for (int i = 0; i < 4; ++i) {
    float sh = b2f(gada[gb + c + i]);
    float sc = b2f(gada[gb + 1024 + c + i]);
    ms[idx + i] = f2b(b2f(lnx[idx + i]) * (1.f + sc) + sh);
  }
}

__global__ __launch_bounds__(256) void ln_mod(
    const float* __restrict__ x1, const us* __restrict__ gada, us* __restrict__ m2) {
  const int row = blockIdx.x;
  const float* xp = x1 + (size_t)row * 1024;
  const int t = threadIdx.x;
  float v[4]; float s = 0.f, ss = 0.f;
#pragma unroll
  for (int i = 0; i < 4; ++i) { float x = xp[i * 256 + t]; v[i] = x; s += x; ss += x * x; }
  for (int o = 32; o; o >>= 1) { s += __shfl_down(s, o); ss += __shfl_down(ss, o); }
  __shared__ float red[2][4];
  const int wv = t >> 6, lane = t & 63;
  if (lane == 0) { red[0][wv] = s; red[1][wv] = ss; }
  __syncthreads();
  s = red[0][0] + red[0][1] + red[0][2] + red[0][3];
  ss = red[1][0] + red[1][1] + red[1][2] + red[1][3];
  const float mean = s * (1.f / 1024.f);
  const float var = fmaxf(ss * (1.f / 1024.f) - mean * mean, 0.f);
  const float rstd = rsqrtf(var + 1e-6f);
  const size_t gb = (size_t)row * 6144;
#pragma unroll
  for (int i = 0; i < 4; ++i) {
    int c = i * 256 + t;
    float n = (v[i] - mean) * rstd;
    float sh = b2f(gada[gb + 3072 + c]);
    float sc = b2f(gada[gb + 4096 + c]);
    m2[(size_t)row * 1024 + c] = f2b(n * (1.f + sc) + sh);
  }
}

// ---------------------------------------------------------------------------
// MFMA GEMM with counted-vmcnt double-buffer pipeline (r6-proven structure).
// ---------------------------------------------------------------------------
enum { EPI_BF16 = 0, EPI_SILU, EPI_GELU, EPI_GATE_XRES, EPI_GATE_OUT };

template <int EPI>
DEVI void gemm_epi(float v, int gmr, int gn, int N, void* out,
                   const us* gate, const void* res0, const void* res1,
                   const int* oflags) {
  const size_t oi = (size_t)gmr * N + gn;
  if constexpr (EPI == EPI_BF16) {
    ((us*)out)[oi] = f2b(v);
  } else if constexpr (EPI == EPI_SILU) {
    ((us*)out)[oi] = f2b(v / (1.f + __expf(-v)));
  } else if constexpr (EPI == EPI_GELU) {
    float u = 0.7978845608028654f * (v + 0.044715f * v * v * v);
    float th = 1.f - 2.f / (__expf(2.f * u) + 1.f);
    ((us*)out)[oi] = f2b(0.5f * v * (1.f + th));
  } else if constexpr (EPI == EPI_GATE_XRES) {
    float g = b2f(gate[(size_t)gmr * 6144 + gn]);
    const void* xr = (gmr < 2048) ? res0 : res1;
    size_t xi = (size_t)(gmr & 2047) * 1024 + gn;
    float x = oflags[0] ? ((const float*)xr)[xi] : b2f(((const us*)xr)[xi]);
    ((float*)out)[oi] = x + g * v;
  } else {
    float g = b2f(gate[(size_t)gmr * 6144 + gn]);
    float x = ((const float*)res0)[oi];
    float r2 = x + g * v;
    if (oflags[0]) ((float*)out)[oi] = r2;
    else ((us*)out)[oi] = f2b(r2);
  }
}

template <int EPI>
__global__ __launch_bounds__(256) void gemm_bt(
    const us* __restrict__ A, const us* __restrict__ BT,
    const us* __restrict__ bias, void* __restrict__ out,
    int M, int N, int K,
    const us* __restrict__ gate,
    const void* __restrict__ res0, const void* __restrict__ res1,
    const int* __restrict__ oflags) {
  __shared__ __attribute__((aligned(16))) us As[2][128 * 32];
  __shared__ __attribute__((aligned(16))) us Bs[2][128 * 32];
  const int m0 = blockIdx.x * 128, n0 = blockIdx.y * 128;
  const int t = threadIdx.x;
  const int wave = t >> 6, lane = t & 63;
  const int wm = (wave >> 1) * 64, wn = (wave & 1) * 64;
  const int l16 = lane & 15, quad = lane >> 4;
  f32x4 acc[4][4] = {};

  const int lr = lane >> 2, lc = (lane & 3) * 8;
  const us* gA = A + (size_t)(m0 + wave * 32 + lr) * K + lc;
  const us* gB = BT + (size_t)(n0 + wave * 32 + lr) * K + lc;
  const int wo = wave * 1024;

#define STAGE_BT(buf, k)                                    \
  { us* pA = &As[buf][wo]; us* pB = &Bs[buf][wo];           \
    gl2lds16(gA + (k), pA);                                 \
    gl2lds16(gA + (size_t)16 * K + (k), pA + 512);          \
    gl2lds16(gB + (k), pB);                                 \
    gl2lds16(gB + (size_t)16 * K + (k), pB + 512); }

  STAGE_BT(0, 0);
  STAGE_BT(1, 32);
  const int NK = K >> 5;
  int cur = 0;
  for (int i = 0; i < NK - 1; ++i) {
    asm volatile("s_waitcnt vmcnt(4)\n\ts_barrier" ::: "memory");
    bf16x8 af[4], bfv[4];
#pragma unroll
    for (int x = 0; x < 4; ++x) af[x] = *(const bf16x8*)(const void*)&As[cur][(wm + x * 16 + l16) * 32 + quad * 8];
#pragma unroll
    for (int j = 0; j < 4; ++j) bfv[j] = *(const bf16x8*)(const void*)&Bs[cur][(wn + j * 16 + l16) * 32 + quad * 8];
    asm volatile("s_waitcnt lgkmcnt(0)\n\ts_barrier" ::: "memory");
    if (i + 2 < NK) STAGE_BT(cur, (i + 2) * 32);
#pragma unroll
    for (int x = 0; x < 4; ++x)
#pragma unroll
      for (int j = 0; j < 4; ++j)
        acc[x][j] = __builtin_amdgcn_mfma_f32_16x16x32_bf16(af[x], bfv[j], acc[x][j], 0, 0, 0);
    cur ^= 1;
  }
  asm volatile("s_waitcnt vmcnt(0)\n\ts_barrier" ::: "memory");
  {
    bf16x8 af[4], bfv[4];
#pragma unroll
    for (int x = 0; x < 4; ++x) af[x] = *(const bf16x8*)(const void*)&As[cur][(wm + x * 16 + l16) * 32 + quad * 8];
#pragma unroll
    for (int j = 0; j < 4; ++j) bfv[j] = *(const bf16x8*)(const void*)&Bs[cur][(wn + j * 16 + l16) * 32 + quad * 8];
#pragma unroll
    for (int x = 0; x < 4; ++x)
#pragma unroll
      for (int j = 0; j < 4; ++j)
        acc[x][j] = __builtin_amdgcn_mfma_f32_16x16x32_bf16(af[x], bfv[j], acc[x][j], 0, 0, 0);
  }
#undef STAGE_BT

#pragma unroll
  for (int i = 0; i < 4; ++i) {
    const int gm = m0 + wm + i * 16 + quad * 4;
#pragma unroll
    for (int j = 0; j < 4; ++j) {
      const int gn = n0 + wn + j * 16 + l16;
      const float bv = b2f(bias[gn]);
#pragma unroll
      for (int r = 0; r < 4; ++r)
        gemm_epi<EPI>(acc[i][j][r] + bv, gm + r, gn, N, out, gate, res0, res1, oflags);
    }
  }
}

// 128x64-tile variant for N=1024-class GEMMs (2x grid vs 128x128).
template <int EPI>
__global__ __launch_bounds__(256) void gemm_bt64(
    const us* __restrict__ A, const us* __restrict__ BT,
    const us* __restrict__ bias, void* __restrict__ out,
    int M, int N, int K,
    const us* __restrict__ gate,
    const void* __restrict__ res0, const void* __restrict__ res1,
    const int* __restrict__ oflags) {
  __shared__ __attribute__((aligned(16))) us As[2][128 * 32];
  __shared__ __attribute__((aligned(16))) us Bs[2][64 * 32];
  const int m0 = blockIdx.x * 128, n0 = blockIdx.y * 64;
  const int t = threadIdx.x;
  const int wave = t >> 6, lane = t & 63;
  const int wm = (wave >> 1) * 64, wn = (wave & 1) * 32;
  const int l16 = lane & 15, quad = lane >> 4;
  f32x4 acc[4][2] = {};

  const int lr = lane >> 2, lc = (lane & 3) * 8;
  const us* gA = A + (size_t)(m0 + wave * 32 + lr) * K + lc;
  const us* gB = BT + (size_t)(n0 + wave * 16 + lr) * K + lc;
  const int woA = wave * 1024, woB = wave * 512;

#define STAGE_BT64(buf, k)                                  \
  { us* pA = &As[buf][woA];                                 \
    gl2lds16(gA + (k), pA);                                 \
    gl2lds16(gA + (size_t)16 * K + (k), pA + 512);          \
    gl2lds16(gB + (k), &Bs[buf][woB]); }

  STAGE_BT64(0, 0);
  STAGE_BT64(1, 32);
  const int NK = K >> 5;
  int cur = 0;
  for (int i = 0; i < NK - 1; ++i) {
    asm volatile("s_waitcnt vmcnt(3)\n\ts_barrier" ::: "memory");
    bf16x8 af[4], bfv[2];
#pragma unroll
    for (int x = 0; x < 4; ++x) af[x] = *(const bf16x8*)(const void*)&As[cur][(wm + x * 16 + l16) * 32 + quad * 8];
#pragma unroll
    for (int j = 0; j < 2; ++j) bfv[j] = *(const bf16x8*)(const void*)&Bs[cur][(wn + j * 16 + l16) * 32 + quad * 8];
    asm volatile("s_waitcnt lgkmcnt(0)\n\ts_barrier" ::: "memory");
    if (i + 2 < NK) STAGE_BT64(cur, (i + 2) * 32);
#pragma unroll
    for (int x = 0; x < 4; ++x)
#pragma unroll
      for (int j = 0; j < 2; ++j)
        acc[x][j] = __builtin_amdgcn_mfma_f32_16x16x32_bf16(af[x], bfv[j], acc[x][j], 0, 0, 0);
    cur ^= 1;
  }
  asm volatile("s_waitcnt vmcnt(0)\n\ts_barrier" ::: "memory");
  {
    bf16x8 af[4], bfv[2];
#pragma unroll
    for (int x = 0; x < 4; ++x) af[x] = *(const bf16x8*)(const void*)&As[cur][(wm + x * 16 + l16) * 32 + quad * 8];
#pragma unroll
    for (int j = 0; j < 2; ++j) bfv[j] = *(const bf16x8*)(const void*)&Bs[cur][(wn + j * 16 + l16) * 32 + quad * 8];
#pragma unroll
    for (int x = 0; x < 4; ++x)
#pragma unroll
      for (int j = 0; j < 2; ++j)
        acc[x][j] = __builtin_amdgcn_mfma_f32_16x16x32_bf16(af[x], bfv[j], acc[x][j], 0, 0, 0);
  }
#undef STAGE_BT64

#pragma unroll
  for (int i = 0; i < 4; ++i) {
    const int gm = m0 + wm + i * 16 + quad * 4;
#pragma unroll
    for (int j = 0; j < 2; ++j) {
      const int gn = n0 + wn + j * 16 + l16;
      const float bv = b2f(bias[gn]);
#pragma unroll
      for (int r = 0; r < 4; ++r)
        gemm_epi<EPI>(acc[i][j][r] + bv, gm + r, gn, N, out, gate, res0, res1, oflags);
    }
  }
}

// ---------------------------------------------------------------------------
// MFMA flash attention: 128-key rounds (paired 64-chunks). Halves barriers
// and online-softmax state updates per key vs 64-key rounds. Serial stage
// between barriers (r6-proven, spill-free). Separate P buffer -> no mid
// barrier (P is wave-local: each wave writes/reads only its 16-row stripe).
// LDS: K[2]+V[2] (36 KB) + P[64][136] (17 KB) = 53 KB; 3 blocks/CU cap,
// grid 512 = 2/CU (unchanged).
// ---------------------------------------------------------------------------
struct AttnState { float m[4], l[4]; f32x4 o[4]; };

DEVI void st_init(AttnState& s) {
#pragma unroll
  for (int r = 0; r < 4; ++r) { s.m[r] = NEGINF; s.l[r] = 0.f; s.o[r] = f32x4{}; }
}

// Stage a 64-row x 64-col bf16 tile into LDS [64][72] (256 threads, 2 iters).
DEVI void stage64(us* __restrict__ dst, const us* __restrict__ src,
                  int strideUs, int t) {
#pragma unroll
  for (int it = 0; it < 2; ++it) {
    const int id = it * 256 + t;
    const int row = id >> 3, c8 = (id & 7) * 8;
    *(uint4*)&dst[row * 72 + c8] = *(const uint4*)(src + (size_t)row * strideUs + c8);
  }
}

// One 128-key round: QK over two K-chunks, fused online softmax, PV over
// two V-chunks. ma/mb = per-r key-visibility masks for chunk A/B.
template <bool MASKED>
DEVI void attn_round2(const us* __restrict__ Kb0, const us* __restrict__ Kb1,
                      const us* __restrict__ Vb0, const us* __restrict__ Vb1,
                      us* __restrict__ Pb, const ull* ma, const ull* mb,
                      bf16x8 aq0, bf16x8 aq1, AttnState& st,
                      int wv, int l16, int quad) {
  f32x4 s[8];
  __builtin_amdgcn_s_setprio(1);
#pragma unroll
  for (int j = 0; j < 8; ++j) {
    const us* kbuf = (j < 4) ? Kb0 : Kb1;
    const int row = (j & 3) * 16 + l16;
    bf16x8 bk0 = *(const bf16x8*)(const void*)&kbuf[row * 72 + quad * 8];
    bf16x8 bk1 = *(const bf16x8*)(const void*)&kbuf[row * 72 + 32 + quad * 8];
    f32x4 z = {};
    z = __builtin_amdgcn_mfma_f32_16x16x32_bf16(aq0, bk0, z, 0, 0, 0);
    z = __builtin_amdgcn_mfma_f32_16x16x32_bf16(aq1, bk1, z, 0, 0, 0);
    s[j] = z;
  }
  __builtin_amdgcn_s_setprio(0);
  const float CE = 0.18033688011112042f;  // 0.125 * log2(e)
#pragma unroll
  for (int r = 0; r < 4; ++r) {
    float mx = s[0][r];
#pragma unroll
    for (int j = 1; j < 8; ++j) mx = fmaxf(mx, s[j][r]);
#pragma unroll
    for (int o2 = 8; o2; o2 >>= 1) mx = fmaxf(mx, __shfl_xor(mx, o2));
    const float mn = fmaxf(st.m[r], mx);
    const float alpha = exp2f((st.m[r] - mn) * CE);  // -inf start -> 0
    const float mnC = mn * CE;
    float rs = 0.f;
#pragma unroll
    for (int j = 0; j < 8; ++j) {
      float p = exp2f(__builtin_fmaf(s[j][r], CE, -mnC));
      if constexpr (MASKED) {
        const ull act = (j < 4) ? ma[r] : mb[r];
        p = ((act >> ((j & 3) * 16 + l16)) & 1ull) ? p : 0.f;
      }
      rs += p;
      ((__bf16*)Pb)[(wv * 16 + quad * 4 + r) * 136 + j * 16 + l16] = (__bf16)p;
    }
#pragma unroll
    for (int o2 = 8; o2; o2 >>= 1) rs += __shfl_xor(rs, o2);
    st.m[r] = mn;
    st.l[r] = st.l[r] * alpha + rs;
#pragma unroll
    for (int jd = 0; jd < 4; ++jd) st.o[jd][r] *= alpha;
  }
  bf16x8 ap[4];
#pragma unroll
  for (int kk = 0; kk < 4; ++kk)
    ap[kk] = *(const bf16x8*)(const void*)&Pb[(wv * 16 + l16) * 136 + kk * 32 + quad * 8];
  __builtin_amdgcn_s_setprio(1);
#pragma unroll
  for (int jd = 0; jd < 4; ++jd) {
    const int row = (jd * 16 + l16) * 72;
    bf16x8 v0 = *(const bf16x8*)(const void*)&Vb0[row + quad * 8];
    bf16x8 v1 = *(const bf16x8*)(const void*)&Vb0[row + 32 + quad * 8];
    bf16x8 v2 = *(const bf16x8*)(const void*)&Vb1[row + quad * 8];
    bf16x8 v3 = *(const bf16x8*)(const void*)&Vb1[row + 32 + quad * 8];
    st.o[jd] = __builtin_amdgcn_mfma_f32_16x16x32_bf16(ap[0], v0, st.o[jd], 0, 0, 0);
    st.o[jd] = __builtin_amdgcn_mfma_f32_16x16x32_bf16(ap[1], v1, st.o[jd], 0, 0, 0);
    st.o[jd] = __builtin_amdgcn_mfma_f32_16x16x32_bf16(ap[2], v2, st.o[jd], 0, 0, 0);
    st.o[jd] = __builtin_amdgcn_mfma_f32_16x16x32_bf16(ap[3], v3, st.o[jd], 0, 0, 0);
  }
  __builtin_amdgcn_s_setprio(0);
}

DEVI void attn_write(us* __restrict__ y, const AttnState& st, int rowAbs,
                     int h, int l16, int quad) {
#pragma unroll
  for (int r = 0; r < 4; ++r) {
    const float inv = (st.l[r] > 0.f) ? 1.f / st.l[r] : 0.f;
#pragma unroll
    for (int jd = 0; jd < 4; ++jd)
      y[(size_t)(rowAbs + quad * 4 + r) * 1024 + h * 64 + jd * 16 + l16] =
          f2b(st.o[jd][r] * inv);
  }
}

// Cross: 256 keys = 2 rounds of 128; no masks.
__global__ __launch_bounds__(256) void cross_attn_mfma(
    const us* __restrict__ q, const us* __restrict__ kv,
    const us* __restrict__ vT, us* __restrict__ y) {
  __shared__ __attribute__((aligned(16))) us Kb[2][64 * 72];
  __shared__ __attribute__((aligned(16))) us Vb[2][64 * 72];
  __shared__ __attribute__((aligned(16))) us Pb[64 * 136];
  const int bid = blockIdx.x;
  const int xcd = bid & 7, tmp = bid >> 3;
  const int tt = tmp & 15, gq = tmp >> 4;
  const int g = gq * 8 + xcd;          // (st,b,h) group
  const int strm = g >> 5, b = (g >> 4) & 1, h = g & 15;
  const int t = threadIdx.x, wv = t >> 6, lane = t & 63;
  const int l16 = lane & 15, quad = lane >> 4;
  const int rowbase = strm * 2048 + b * 1024 + tt * 64 + wv * 16;
  const us* qp = q + (size_t)(rowbase + l16) * 1024 + h * 64 + quad * 8;
  bf16x8 aq0 = *(const bf16x8*)(qp);
  bf16x8 aq1 = *(const bf16x8*)(qp + 32);
  const us* kb = kv + (size_t)b * (256 * 2048) + h * 64;
  const us* vb = vT + (size_t)(b * 16 + h) * (64 * 256);
  AttnState st; st_init(st);
  for (int rnd = 0; rnd < 2; ++rnd) {
    const int s0 = rnd * 128;
    __syncthreads();
    stage64(Kb[0], kb + (size_t)s0 * 2048, 2048, t);
    stage64(Kb[1], kb + (size_t)(s0 + 64) * 2048, 2048, t);
    stage64(Vb[0], vb + s0, 256, t);
    stage64(Vb[1], vb + s0 + 64, 256, t);
    __syncthreads();
    attn_round2<false>(Kb[0], Kb[1], Vb[0], Vb[1], Pb, nullptr, nullptr,
                       aq0, aq1, st, wv, l16, quad);
  }
  attn_write(y, st, rowbase, h, l16, quad);
}

// Star: pairs (ck0, ck0+1); ck0 always even so ck0+1 <= 15 (valid memory);
// chunks past the diagonal are mask-zeroed (shift-invariant softmax makes
// their raw scores harmless).
DEVI void star_body(us (*Kb)[64 * 72], us (*Vb)[64 * 72], us* Pb,
                    const us* qkv, const us* vT,
                    const ull* depb, us* y, int b, int h, int tt, int t) {
  const int wv = t >> 6, lane = t & 63;
  const int l16 = lane & 15, quad = lane >> 4;
  const int t0 = tt * 64;
  const int rowbase = b * 1024 + t0 + wv * 16;
  const us* qp = qkv + (size_t)(rowbase + l16) * 3072 + h * 64 + quad * 8;
  bf16x8 aq0 = *(const bf16x8*)(qp);
  bf16x8 aq1 = *(const bf16x8*)(qp + 32);
  const us* kb = qkv + (size_t)(b * 1024) * 3072 + 1024 + h * 64;
  const us* vb = vT + (size_t)(b * 16 + h) * 65536;
  AttnState st; st_init(st);
  for (int ck0 = 0; ck0 <= tt; ck0 += 2) {
    __syncthreads();
    stage64(Kb[0], kb + (size_t)ck0 * 64 * 3072, 3072, t);
    stage64(Kb[1], kb + (size_t)(ck0 + 1) * 64 * 3072, 3072, t);
    stage64(Vb[0], vb + ck0 * 64, 1024, t);
    stage64(Vb[1], vb + (ck0 + 1) * 64, 1024, t);
    __syncthreads();
    ull ma[4], mb[4];
#pragma unroll
    for (int r = 0; r < 4; ++r) {
      const size_t mbase = (size_t)(rowbase + quad * 4 + r) * 16;
      const int idx = wv * 16 + quad * 4 + r;  // trow within tile
      ull dA = depb[mbase + ck0];
      if (ck0 == tt) dA &= (2ull << idx) - 1ull;
      ma[r] = dA;
      ull dB = 0;
      if (ck0 + 1 <= tt) {
        dB = depb[mbase + ck0 + 1];
        if (ck0 + 1 == tt) dB &= (2ull << idx) - 1ull;
      }
      mb[r] = dB;
    }
    attn_round2<true>(Kb[0], Kb[1], Vb[0], Vb[1], Pb, ma, mb,
                      aq0, aq1, st, wv, l16, quad);
  }
  attn_write(y, st, rowbase, h, l16, quad);
}

// Hat: slot walk (slot = 2*ck + part) consumed two at a time; odd remainder
// duplicates slot A into the B half with a zero mask.
DEVI void hat_body(us (*Kb)[64 * 72], us (*Vb)[64 * 72], us* Pb,
                   const us* qkv, const us* vsT, const us* vhT,
                   const ull* starb, const ull* hatb, const ull* depb,
                   const int* bflags, us* y, int b, int h, int tt, int t) {
  const int wv = t >> 6, lane = t & 63;
  const int l16 = lane & 15, quad = lane >> 4;
  const int t0 = tt * 64;
  const int rowbase = b * 1024 + t0 + wv * 16;
  const us* qp = qkv + (size_t)(2048 + rowbase + l16) * 3072 + h * 64 + quad * 8;
  bf16x8 aq0 = *(const bf16x8*)(qp);
  bf16x8 aq1 = *(const bf16x8*)(qp + 32);
  const us* ksb = qkv + (size_t)(b * 1024) * 3072 + 1024 + h * 64;
  const us* khb = qkv + (size_t)(2048 + b * 1024) * 3072 + 1024 + h * 64;
  const us* vsb = vsT + (size_t)(b * 16 + h) * 65536;
  const us* vhb = vhT + (size_t)(b * 16 + h) * 65536;
  AttnState st; st_init(st);
  unsigned msk = 0;
  for (int ck = 0; ck < 16; ++ck) {
    int f = bflags[(b * 16 + tt) * 16 + ck];
    msk |= (unsigned)(f & 3) << (2 * ck);
  }
  while (msk) {
    const int sa = (int)__builtin_ctz(msk); msk &= msk - 1;
    int sb = -1;
    if (msk) { sb = (int)__builtin_ctz(msk); msk &= msk - 1; }
    const int cka = sa >> 1, pa = sa & 1;
    const int ckb = (sb >= 0) ? (sb >> 1) : cka;
    const int pb = (sb >= 0) ? (sb & 1) : pa;
    __syncthreads();
    stage64(Kb[0], (pa ? khb : ksb) + (size_t)cka * 64 * 3072, 3072, t);
    stage64(Kb[1], (pb ? khb : ksb) + (size_t)ckb * 64 * 3072, 3072, t);
    stage64(Vb[0], (pa ? vhb : vsb) + cka * 64, 1024, t);
    stage64(Vb[1], (pb ? vhb : vsb) + ckb * 64, 1024, t);
    __syncthreads();
    ull ma[4], mb[4];
#pragma unroll
    for (int r = 0; r < 4; ++r) {
      const size_t mbase = (size_t)(rowbase + quad * 4 + r) * 16;
      ma[r] = (pa ? hatb : starb)[mbase + cka] & depb[mbase + cka];
      mb[r] = (sb >= 0) ? ((pb ? hatb : starb)[mbase + ckb] & depb[mbase + ckb]) : 0ull;
    }
    attn_round2<true>(Kb[0], Kb[1], Vb[0], Vb[1], Pb, ma, mb,
                      aq0, aq1, st, wv, l16, quad);
  }
  attn_write(y, st, 2048 + rowbase, h, l16, quad);
}

// XCD-swizzled merged self-attention with complementary-pair load balance.
__global__ __launch_bounds__(256) void self_attn_mfma(
    const us* __restrict__ qkv,
    const us* __restrict__ vstT, const us* __restrict__ vhtT,
    const ull* __restrict__ sbits, const ull* __restrict__ hbits,
    const ull* __restrict__ dbits, const int* __restrict__ bflags,
    us* __restrict__ y) {
  __shared__ __attribute__((aligned(16))) us Kb[2][64 * 72];
  __shared__ __attribute__((aligned(16))) us Vb[2][64 * 72];
  __shared__ __attribute__((aligned(16))) us Pb[64 * 136];
  const int bid = blockIdx.x;
  const int xcd = bid & 7, tmp = bid >> 3;
  const int pr = tmp & 7, gq = tmp >> 3;
  const int g = gq * 8 + xcd;
  const int ttA = pr, ttB = 15 - pr;
  const int t = threadIdx.x;
  if (g < 32) {
    star_body(Kb, Vb, Pb, qkv, vstT, dbits, y, g >> 4, g & 15, ttA, t);
    star_body(Kb, Vb, Pb, qkv, vstT, dbits, y, g >> 4, g & 15, ttB, t);
  } else {
    const int g2 = g - 32;
    hat_body(Kb, Vb, Pb, qkv, vstT, vhtT, sbits, hbits, dbits, bflags,
             y, g2 >> 4, g2 & 15, ttA, t);
    hat_body(Kb, Vb, Pb, qkv, vstT, vhtT, sbits, hbits, dbits, bflags,
             y, g2 >> 4, g2 & 15, ttB, t);
  }
}

// ---------------------------------------------------------------------------
extern "C" void kernel_launch(void* const* d_in, const int* in_sizes, int n_in,
                              void* d_out, int out_size, void* d_ws, size_t ws_size,
                              hipStream_t stream) {
  const void* xs = d_in[0];
  const void* xh = d_in[1];
  const void* cc = d_in[2];
  const void* mstar = d_in[3];
  const void* mhat = d_in[4];
  const void* mdep = d_in[5];
  const void* ng = d_in[6];
  const void* nb = d_in[7];
  const void* Wq = d_in[8];
  const void* bq = d_in[9];
  const void* Wkv = d_in[10];
  const void* bkv = d_in[11];
  const void* Wco = d_in[12];
  const void* bco = d_in[13];
  const void* Wada = d_in[14];
  const void* bada = d_in[15];
  const void* Wqkv = d_in[16];
  const void* bqkv = d_in[17];
  const void* Wo = d_in[18];
  const void* bo = d_in[19];
  const void* W1 = d_in[20];
  const void* b1 = d_in[21];
  const void* W2 = d_in[22];
  const void* b2 = d_in[23];
  (void)in_sizes; (void)n_in; (void)out_size; (void)ws_size;

  char* ws = (char*)d_ws;
  size_t off = 0;
  auto alloc = [&](size_t bytes) -> char* {
    char* p = ws + off;
    off += (bytes + 255) & ~(size_t)255;
    return p;
  };
  int* flags = (int*)alloc(256);
  int* bflags = (int*)alloc(512 * 4);
  us* smallb = (us*)alloc(21504 * 2);
  us* ngb = smallb, *nbb = smallb + 1024, *bqb = smallb + 2048,
      *bkvb = smallb + 3072, *bcob = smallb + 5120, *badab = smallb + 6144,
      *bqkvb = smallb + 12288, *bob = smallb + 15360, *b1b = smallb + 16384,
      *b2b = smallb + 20480;
  us* WqT = (us*)alloc(1048576ull * 2);
  us* WkvT = (us*)alloc(2097152ull * 2);
  us* WcoT = (us*)alloc(1048576ull * 2);
  us* WadaT = (us*)alloc(6291456ull * 2);
  us* WqkvT = (us*)alloc(3145728ull * 2);
  us* WoT = (us*)alloc(1048576ull * 2);
  us* W1T = (us*)alloc(4194304ull * 2);
  us* W2T = (us*)alloc(4194304ull * 2);
  us* xn = (us*)alloc(4194304ull * 2);
  us* qb = (us*)alloc(4194304ull * 2);
  us* kvb = (us*)alloc(1048576ull * 2);
  us* gada = (us*)alloc(25165824ull * 2);
  us* msb = (us*)alloc(4194304ull * 2);
  us* qkvb = (us*)alloc(12582912ull * 2);
  float* x1 = (float*)alloc(4194304ull * 4);
  us* hid = (us*)alloc(16777216ull * 2);
  ull* mb = (ull*)alloc(3ull * 32768 * 8);
  us* kvT = (us*)alloc(524288ull * 2);
  us* vstT = (us*)alloc(2097152ull * 2);
  us* vhtT = (us*)alloc(2097152ull * 2);

  ull* sbits = mb;
  ull* hbits = mb + 32768;
  ull* dbits = mb + 65536;
  us* ccb = hid;              // dead before hid written
  us* lnx = hid + 1048576;    // dead before hid written
  us* yca = xn;
  us* silub = qb;
  us* yat = msb;

  dim3 blk(256);
  detect_flags<<<1, blk, 0, stream>>>((const unsigned int*)xs, (const unsigned int*)mdep, flags);

  cvt_bf16<<<512, blk, 0, stream>>>(cc, ccb, 524288, flags);
  P10 ps10; ps10.p[0] = ng; ps10.p[1] = nb; ps10.p[2] = bq; ps10.p[3] = bkv;
  ps10.p[4] = bco; ps10.p[5] = bada; ps10.p[6] = bqkv; ps10.p[7] = bo;
  ps10.p[8] = b1; ps10.p[9] = b2;
  cvt_small<<<84, blk, 0, stream>>>(ps10, smallb, flags);

  transpose_cvt64<<<dim3(16, 16), blk, 0, stream>>>(Wq, WqT, 1024, 1024, flags);
  transpose_cvt64<<<dim3(16, 32), blk, 0, stream>>>(Wkv, WkvT, 1024, 2048, flags);
  transpose_cvt64<<<dim3(16, 16), blk, 0, stream>>>(Wco, WcoT, 1024, 1024, flags);
  transpose_cvt64<<<dim3(16, 96), blk, 0, stream>>>(Wada, WadaT, 1024, 6144, flags);
  transpose_cvt64<<<dim3(16, 48), blk, 0, stream>>>(Wqkv, WqkvT, 1024, 3072, flags);
  transpose_cvt64<<<dim3(16, 16), blk, 0, stream>>>(Wo, WoT, 1024, 1024, flags);
  transpose_cvt64<<<dim3(16, 64), blk, 0, stream>>>(W1, W1T, 1024, 4096, flags);
  transpose_cvt64<<<dim3(64, 16), blk, 0, stream>>>(W2, W2T, 4096, 1024, flags);

  P3 ps3; ps3.p[0] = mstar; ps3.p[1] = mhat; ps3.p[2] = mdep;
  pack_mask3<<<dim3(512, 3), blk, 0, stream>>>(ps3, mb, flags);
  hat_blockflags<<<32, blk, 0, stream>>>(sbits, hbits, bflags);

  ln_affine<<<4096, blk, 0, stream>>>(xs, xh, ngb, nbb, lnx, xn, flags);
  gemm_bt64<EPI_BF16><<<dim3(32, 16), blk, 0, stream>>>(xn, WqT, bqb, qb, 4096, 1024, 1024, nullptr, nullptr, nullptr, nullptr);
  gemm_bt64<EPI_BF16><<<dim3(4, 32), blk, 0, stream>>>(ccb, WkvT, bkvb, kvb, 512, 2048, 1024, nullptr, nullptr, nullptr, nullptr);
  vtrans<<<dim3(4, 32), blk, 0, stream>>>(kvb, kvT, 256, 2048, 1024, 0);
  cross_attn_mfma<<<1024, blk, 0, stream>>>(qb, kvb, kvT, yca);
  gemm_bt64<EPI_SILU><<<dim3(32, 16), blk, 0, stream>>>(yca, WcoT, bcob, silub, 4096, 1024, 1024, nullptr, nullptr, nullptr, nullptr);
  gemm_bt<EPI_BF16><<<dim3(32, 48), blk, 0, stream>>>(silub, WadaT, badab, gada, 4096, 6144, 1024, nullptr, nullptr, nullptr, nullptr);
  mod_ms<<<4096, blk, 0, stream>>>(lnx, gada, msb);
  gemm_bt<EPI_BF16><<<dim3(32, 24), blk, 0, stream>>>(msb, WqkvT, bqkvb, qkvb, 4096, 3072, 1024, nullptr, nullptr, nullptr, nullptr);
  vtrans_qkv<<<dim3(16, 32, 2), blk, 0, stream>>>(qkvb, vstT, vhtT);
  self_attn_mfma<<<512, blk, 0, stream>>>(qkvb, vstT, vhtT, sbits, hbits, dbits, bflags, yat);
  gemm_bt64<EPI_GATE_XRES><<<dim3(32, 16), blk, 0, stream>>>(yat, WoT, bob, x1, 4096, 1024, 1024, gada + 2048, xs, xh, flags);
  ln_mod<<<4096, blk, 0, stream>>>(x1, gada, msb);
  gemm_bt<EPI_GELU><<<dim3(32, 32), blk, 0, stream>>>(msb, W1T, b1b, hid, 4096, 4096, 1024, nullptr, nullptr, nullptr, nullptr);
  gemm_bt64<EPI_GATE_OUT><<<dim3(32, 16), blk, 0, stream>>>(hid, W2T, b2b, d_out, 4096, 1024, 4096, gada + 5120, x1, nullptr, flags);
}